// Round 4
// baseline (250.263 us; speedup 1.0000x reference)
//
#include <hip/hip_runtime.h>
#include <hip/hip_cooperative_groups.h>
#include <hip/hip_bf16.h>
#include <math.h>

namespace cg = cooperative_groups;

#define K_B 32
#define NRELD 16
#define PSZ 128
#define HID 768

using bf16x8 = __attribute__((ext_vector_type(8))) short;
using f32x4  = __attribute__((ext_vector_type(4))) float;

__device__ __forceinline__ unsigned int f2bf(float x) {   // fp32 -> bf16 bits (RNE)
    unsigned int u = __float_as_uint(x);
    return (u + 0x7fffu + ((u >> 16) & 1u)) >> 16;
}
__device__ __forceinline__ float bf2f(unsigned short b) {
    return __uint_as_float(((unsigned int)b) << 16);
}

struct MegaParams {
    const float* inst; const float* rel; const int* relIds;
    const int* labels; const float* P0;
    unsigned short *S_bf, *P0_bf, *P0T_bf, *pt_bf, *v_bf, *w_bf;
    float *prop, *lossAcc;
    int *rowflag, *cntRow;
    float *outLogits, *outLoss, *outProto;
};

// =========================================================================
// Single cooperative kernel: 288 blocks x 256 thr, 4 phases w/ grid.sync()
// =========================================================================
__global__ __launch_bounds__(256) void k_mega(MegaParams P)
{
    cg::grid_group grid = cg::this_grid();
    __shared__ unsigned short sh[32*768 + 64*128];   // 64 KB workhorse
    __shared__ int lab[32], rankS[32], luS[32], ownS[128];
    __shared__ int hist[2][128], redS[256];
    __shared__ float redF[256];
    __shared__ float nActS[16];
    __shared__ int kS2[16];
    const int bid = blockIdx.x, t = threadIdx.x;
    const int wave = t >> 6, lane = t & 63;

    // ---------------- Phase 0: masks/histograms + bf16 conversions --------
    if (t < 32) lab[t] = P.labels[t];
    if (t < 128) ownS[t] = -1;
    hist[t >> 7][t & 127] = 0;
    __syncthreads();
    if (t < 32) { int rk = 0; for (int j = 0; j < 32; ++j) rk += (lab[j] < lab[t]); rankS[t] = rk; }
    __syncthreads();
    if (t < 32) luS[rankS[t]] = lab[t];
    __syncthreads();
    if (t < 32) ownS[luS[t]] = t;
    __syncthreads();

    if (bid < 256) {
        // two (k,r) rows per block: row = bid*2 + (t>>7)
        int half = t >> 7, j = t & 127;
        int row = bid*2 + half;
        int k = row >> 4, r = row & 15;
        int id = P.relIds[((size_t)rankS[k]*NRELD + r)*PSZ + j];
        int isv = (id != PSZ);
        if (isv) atomicAdd(&hist[half][id], 1);
        redS[t] = id + (isv << 20);          // rowsum (<2^20) | cnt<<20
        __syncthreads();
        for (int off = 64; off; off >>= 1) {
            if (j < off) redS[t] += redS[t + off];
            __syncthreads();
        }
        int rowsum = redS[half << 7] & 0xFFFFF;
        int cnt    = redS[half << 7] >> 20;
        int rf     = (rowsum > 0);
        P.S_bf[(size_t)row*128 + j] = (unsigned short)f2bf(rf ? (float)hist[half][j] : 0.f);
        if (j == 0) { P.rowflag[row] = rf; P.cntRow[row] = cnt; }
    } else {
        // 32 blocks convert P0: 4 rows each
        int pb = (bid - 256) * 4;
        if (t < 192) {
            for (int rr = 0; rr < 4; ++rr) {
                int p = pb + rr;
                float4 v4 = *(const float4*)&P.P0[(size_t)p*HID + t*4];
                unsigned int b0 = f2bf(v4.x), b1 = f2bf(v4.y), b2 = f2bf(v4.z), b3 = f2bf(v4.w);
                uint2 d; d.x = b0 | (b1 << 16); d.y = b2 | (b3 << 16);
                *(uint2*)&P.P0_bf[(size_t)p*HID + t*4] = d;
                P.P0T_bf[(size_t)(t*4+0)*128 + p] = (unsigned short)b0;
                P.P0T_bf[(size_t)(t*4+1)*128 + p] = (unsigned short)b1;
                P.P0T_bf[(size_t)(t*4+2)*128 + p] = (unsigned short)b2;
                P.P0T_bf[(size_t)(t*4+3)*128 + p] = (unsigned short)b3;
                int kk = ownS[p];
                if (kk >= 0) *(uint2*)&P.pt_bf[(size_t)kk*HID + t*4] = d;
            }
        }
    }
    grid.sync();

    // ---------------- Phase 1: v (0..191)  ||  w (192..287) --------------
    if (bid < 192) {
        int r = bid & 15, hs = bid >> 4;
        unsigned short* ptS = sh;            // [k][g], chunk c^=(k&7)
        unsigned short* AS  = sh + 32*768;   // [h][g-tile 128], chunk c^=(h&7)
        for (int i = t; i < 3072; i += 256) {
            int k = i / 96, c = i % 96;
            uint4 d = *(const uint4*)&P.pt_bf[(size_t)k*HID + c*8];
            *(uint4*)&ptS[k*768 + (c ^ (k & 7))*8] = d;
        }
        const int gq = (t & 31) * 4;
        const int hr = t >> 5;
        const size_t relbase = ((size_t)r*HID + hs*64) * HID;
        float4 buf[8];
        #pragma unroll
        for (int rr = 0; rr < 8; ++rr)
            buf[rr] = *(const float4*)&P.rel[relbase + (size_t)(hr + rr*8)*HID + gq];
        f32x4 acc[2] = {{0.f,0.f,0.f,0.f},{0.f,0.f,0.f,0.f}};
        const int arow = wave*16 + (lane & 15);
        for (int gt = 0; gt < 6; ++gt) {
            __syncthreads();
            #pragma unroll
            for (int rr = 0; rr < 8; ++rr) {
                int h_l = hr + rr*8;
                float4 v4 = buf[rr];
                int cs = (gq >> 3) ^ (h_l & 7);
                uint2 d; d.x = f2bf(v4.x) | (f2bf(v4.y) << 16);
                d.y = f2bf(v4.z) | (f2bf(v4.w) << 16);
                *(uint2*)&AS[h_l*128 + cs*8 + (gq & 4)] = d;
            }
            __syncthreads();
            if (gt < 5) {
                int gn = gt*128 + 128;
                #pragma unroll
                for (int rr = 0; rr < 8; ++rr)
                    buf[rr] = *(const float4*)&P.rel[relbase + (size_t)(hr + rr*8)*HID + gn + gq];
            }
            #pragma unroll
            for (int kk = 0; kk < 4; ++kk) {
                int cA = (kk*4 + (lane >> 4)) ^ (arow & 7);
                bf16x8 a = *(const bf16x8*)&AS[arow*128 + cA*8];
                #pragma unroll
                for (int nf = 0; nf < 2; ++nf) {
                    int k = nf*16 + (lane & 15);
                    int cB = (gt*16 + kk*4 + (lane >> 4)) ^ (k & 7);
                    bf16x8 b = *(const bf16x8*)&ptS[k*768 + cB*8];
                    acc[nf] = __builtin_amdgcn_mfma_f32_16x16x32_bf16(a, b, acc[nf], 0, 0, 0);
                }
            }
        }
        int h_out = hs*64 + wave*16 + (lane >> 4) * 4;
        #pragma unroll
        for (int nf = 0; nf < 2; ++nf) {
            int k = nf*16 + (lane & 15);
            uint2 d; d.x = f2bf(acc[nf][0]) | (f2bf(acc[nf][1]) << 16);
            d.y = f2bf(acc[nf][2]) | (f2bf(acc[nf][3]) << 16);
            *(uint2*)&P.v_bf[((size_t)k*NRELD + r)*HID + h_out] = d;
        }
    } else {
        int idx = bid - 192;                 // 0..95
        int ms = idx / 12, ns = idx % 12;
        unsigned short* AS2 = sh;
        unsigned short* BS2 = sh + 64*128;
        if (t < 64) *(float4*)&P.prop[idx*256 + t*4] = float4{0.f,0.f,0.f,0.f};
        if (idx == 0 && t == 0) P.lossAcc[0] = 0.f;
        for (int i = t; i < 1024; i += 256) {
            int row = i >> 4, c = i & 15;
            *(uint4*)&AS2[row*128 + (c ^ (row & 7))*8] =
                *(const uint4*)&P.S_bf[(size_t)(ms*64 + row)*128 + c*8];
            *(uint4*)&BS2[row*128 + (c ^ (row & 7))*8] =
                *(const uint4*)&P.P0T_bf[(size_t)(ns*64 + row)*128 + c*8];
        }
        __syncthreads();
        f32x4 acc[4] = {{0.f,0.f,0.f,0.f},{0.f,0.f,0.f,0.f},{0.f,0.f,0.f,0.f},{0.f,0.f,0.f,0.f}};
        int arow = wave*16 + (lane & 15);
        #pragma unroll
        for (int kk = 0; kk < 4; ++kk) {
            int cA = (kk*4 + (lane >> 4)) ^ (arow & 7);
            bf16x8 a = *(const bf16x8*)&AS2[arow*128 + cA*8];
            #pragma unroll
            for (int nf = 0; nf < 4; ++nf) {
                int brow = nf*16 + (lane & 15);
                int cB = (kk*4 + (lane >> 4)) ^ (brow & 7);
                bf16x8 b = *(const bf16x8*)&BS2[brow*128 + cB*8];
                acc[nf] = __builtin_amdgcn_mfma_f32_16x16x32_bf16(a, b, acc[nf], 0, 0, 0);
            }
        }
        int kr0 = ms*64 + wave*16 + (lane >> 4) * 4;
        #pragma unroll
        for (int nf = 0; nf < 4; ++nf) {
            int h = ns*64 + nf*16 + (lane & 15);
            #pragma unroll
            for (int j = 0; j < 4; ++j)
                P.w_bf[(size_t)(kr0 + j)*HID + h] = (unsigned short)f2bf(acc[nf][j]);
        }
    }
    grid.sync();

    // ---------------- Phase 2: prop (0..191)  ||  zz+loss (192..223) -----
    if (bid < 192) {
        int r = bid & 15, gs = bid >> 4;
        unsigned short* WS = sh;             // [k][h], chunk c^=(k&7)
        unsigned short* BS = sh + 32*768;    // [g_l][h-tile 128]
        for (int i = t; i < 3072; i += 256) {
            int k = i / 96, c = i % 96;
            uint4 d = *(const uint4*)&P.w_bf[((size_t)k*NRELD + r)*HID + c*8];
            *(uint4*)&WS[k*768 + (c ^ (k & 7))*8] = d;
        }
        const int gqq = t & 15;
        const int h4  = t >> 4;
        const size_t relb = (size_t)r*HID*HID + (size_t)gs*64;
        float4 buf[8];
        #pragma unroll
        for (int sup = 0; sup < 2; ++sup)
            #pragma unroll
            for (int rr = 0; rr < 4; ++rr)
                buf[sup*4+rr] = *(const float4*)&P.rel[relb + (size_t)(sup*64 + h4*4 + rr)*HID + gqq*4];
        f32x4 acc[2] = {{0.f,0.f,0.f,0.f},{0.f,0.f,0.f,0.f}};
        for (int ht = 0; ht < 6; ++ht) {
            __syncthreads();
            #pragma unroll
            for (int sup = 0; sup < 2; ++sup) {
                #pragma unroll
                for (int i = 0; i < 4; ++i) {
                    int g_l = gqq*4 + i;
                    int hloc = sup*64 + h4*4;
                    unsigned int p0 = f2bf(((const float*)&buf[sup*4+0])[i]);
                    unsigned int p1 = f2bf(((const float*)&buf[sup*4+1])[i]);
                    unsigned int p2 = f2bf(((const float*)&buf[sup*4+2])[i]);
                    unsigned int p3 = f2bf(((const float*)&buf[sup*4+3])[i]);
                    int cs = (hloc >> 3) ^ ((g_l >> 2) & 7);
                    uint2 d; d.x = p0 | (p1 << 16); d.y = p2 | (p3 << 16);
                    *(uint2*)&BS[g_l*128 + cs*8 + (hloc & 4)] = d;
                }
            }
            __syncthreads();
            if (ht < 5) {
                int hn = ht*128 + 128;
                #pragma unroll
                for (int sup = 0; sup < 2; ++sup)
                    #pragma unroll
                    for (int rr = 0; rr < 4; ++rr)
                        buf[sup*4+rr] = *(const float4*)&P.rel[relb + (size_t)(hn + sup*64 + h4*4 + rr)*HID + gqq*4];
            }
            int g_l = wave*16 + (lane & 15);
            #pragma unroll
            for (int kk = 0; kk < 4; ++kk) {
                int cB = (kk*4 + (lane >> 4)) ^ ((g_l >> 2) & 7);
                bf16x8 b = *(const bf16x8*)&BS[g_l*128 + cB*8];
                #pragma unroll
                for (int mf = 0; mf < 2; ++mf) {
                    int arow = mf*16 + (lane & 15);
                    int cA = (ht*16 + kk*4 + (lane >> 4)) ^ (arow & 7);
                    bf16x8 a = *(const bf16x8*)&WS[arow*768 + cA*8];
                    acc[mf] = __builtin_amdgcn_mfma_f32_16x16x32_bf16(a, b, acc[mf], 0, 0, 0);
                }
            }
        }
        int gcol = gs*64 + wave*16 + (lane & 15);
        #pragma unroll
        for (int mf = 0; mf < 2; ++mf) {
            int k0 = mf*16 + (lane >> 4) * 4;
            #pragma unroll
            for (int j = 0; j < 4; ++j)
                atomicAdd(&P.prop[(size_t)(k0 + j)*HID + gcol], acc[mf][j]);
        }
    } else if (bid < 224) {
        int ms = bid - 192;
        unsigned short* AS  = sh;
        unsigned short* BS2 = sh + 16*128;
        f32x4 acc[2] = {{0.f,0.f,0.f,0.f},{0.f,0.f,0.f,0.f}};
        for (int ht = 0; ht < 6; ++ht) {
            int h0 = ht * 128;
            __syncthreads();
            {
                int row = t >> 4, c = t & 15;
                *(uint4*)&AS[row*128 + (c ^ (row & 7))*8] =
                    *(const uint4*)&P.v_bf[(size_t)(ms*16 + row)*HID + h0 + c*8];
                #pragma unroll
                for (int q = 0; q < 8; ++q) {
                    int j2 = t + q*256;
                    int prow = j2 >> 4, c2 = j2 & 15;
                    *(uint4*)&BS2[prow*128 + (c2 ^ (prow & 7))*8] =
                        *(const uint4*)&P.P0_bf[(size_t)prow*HID + h0 + c2*8];
                }
            }
            __syncthreads();
            int arow = lane & 15;
            #pragma unroll
            for (int kk = 0; kk < 4; ++kk) {
                int cA = (kk*4 + (lane >> 4)) ^ (arow & 7);
                bf16x8 a = *(const bf16x8*)&AS[arow*128 + cA*8];
                #pragma unroll
                for (int nf = 0; nf < 2; ++nf) {
                    int brow = wave*32 + nf*16 + (lane & 15);
                    int cB = (kk*4 + (lane >> 4)) ^ (brow & 7);
                    bf16x8 b = *(const bf16x8*)&BS2[brow*128 + cB*8];
                    acc[nf] = __builtin_amdgcn_mfma_f32_16x16x32_bf16(a, b, acc[nf], 0, 0, 0);
                }
            }
        }
        float term = 0.f;
        #pragma unroll
        for (int nf = 0; nf < 2; ++nf) {
            int p = wave*32 + nf*16 + (lane & 15);
            int kr0 = ms*16 + (lane >> 4) * 4;
            #pragma unroll
            for (int j = 0; j < 4; ++j) {
                float S = bf2f(P.S_bf[(size_t)(kr0 + j)*128 + p]);
                if (S != 0.f) {
                    float z = acc[nf][j];
                    float s = 1.f / (1.f + expf(-z));
                    term += S * (logf(expf(1.f - s) + expf(s)) - s);
                }
            }
        }
        redF[t] = term;
        __syncthreads();
        for (int off = 128; off; off >>= 1) {
            if (t < off) redF[t] += redF[t + off];
            __syncthreads();
        }
        if (t == 0) atomicAdd(P.lossAcc, redF[0]);
    }
    grid.sync();

    // ------- Phase 3: proto+logits (0..7)  ||  loss finalize (8) ---------
    if (bid < 8) {
        float* protoS = (float*)sh;          // [16][772] padded
        const int PSTR = 772;
        if (t < 16) {
            int p = bid*16 + t;
            int k = ownS[p];
            float n = 0.f;
            if (k >= 0)
                for (int i = 0; i < 16; ++i) {
                    int rr2 = k*NRELD + i;
                    if (P.rowflag[rr2]) n += (float)P.cntRow[rr2];
                }
            nActS[t] = n; kS2[t] = k;
        }
        __syncthreads();
        for (int it = t; it < 16*192; it += 256) {
            int pl = it / 192, c = it % 192;
            int p = bid*16 + pl;
            float4 old = *(const float4*)&P.P0[(size_t)p*HID + c*4];
            float4 o = old;
            int k = kS2[pl]; float n = nActS[pl];
            if (k >= 0 && n > 0.f) {
                float4 pr = *(const float4*)&P.prop[(size_t)k*HID + c*4];
                float invn = 0.5f / n;
                o.x = 0.5f*old.x + pr.x*invn;
                o.y = 0.5f*old.y + pr.y*invn;
                o.z = 0.5f*old.z + pr.z*invn;
                o.w = 0.5f*old.w + pr.w*invn;
            }
            *(float4*)&P.outProto[(size_t)p*HID + c*4] = o;
            protoS[pl*PSTR + c*4+0] = o.x;
            protoS[pl*PSTR + c*4+1] = o.y;
            protoS[pl*PSTR + c*4+2] = o.z;
            protoS[pl*PSTR + c*4+3] = o.w;
        }
        __syncthreads();
        int b = t & 31, p2 = (t >> 5) * 2;
        const float4* ir = (const float4*)&P.inst[(size_t)b*HID];
        float a0 = 0.f, a1 = 0.f;
        for (int q = 0; q < HID/4; ++q) {
            float4 iv = ir[q];
            float4 pv0 = *(const float4*)&protoS[p2*PSTR + q*4];
            float4 pv1 = *(const float4*)&protoS[(p2+1)*PSTR + q*4];
            float dx = iv.x - pv0.x, dy = iv.y - pv0.y, dz = iv.z - pv0.z, dw = iv.w - pv0.w;
            a0 += dx*dx + dy*dy + dz*dz + dw*dw;
            dx = iv.x - pv1.x; dy = iv.y - pv1.y; dz = iv.z - pv1.z; dw = iv.w - pv1.w;
            a1 += dx*dx + dy*dy + dz*dz + dw*dw;
        }
        P.outLogits[b*PSZ + bid*16 + p2]     = -a0;
        P.outLogits[b*PSZ + bid*16 + p2 + 1] = -a1;
    } else if (bid == 8) {
        float s = 0.f; int tot = 0;
        #pragma unroll
        for (int q = 0; q < 2; ++q) {
            int rr2 = t + 256*q;
            int rf = P.rowflag[rr2];
            tot |= rf;
            if (rf) s += (float)P.cntRow[rr2];
        }
        redF[t] = s; redS[t] = tot;
        __syncthreads();
        for (int off = 128; off; off >>= 1) {
            if (t < off) { redF[t] += redF[t + off]; redS[t] |= redS[t + off]; }
            __syncthreads();
        }
        if (t == 0)
            P.outLoss[0] = redS[0]
                ? (P.lossAcc[0] + (65536.f - redF[0]) * 0.6931471805599453f) * (1.f/65536.f)
                : 0.f;
    }
}

// =========================================================================
// Fallback path (R3 kernels, proven) — used only if cooperative launch fails
// =========================================================================
__global__ __launch_bounds__(192) void k_prep(
        const int* __restrict__ labels, const int* __restrict__ relIds,
        const float* __restrict__ P0,
        unsigned short* __restrict__ S_bf, unsigned short* __restrict__ P0_bf,
        unsigned short* __restrict__ P0T_bf, unsigned short* __restrict__ pt_bf,
        int* __restrict__ rowflag, int* __restrict__ cntRow,
        int* __restrict__ rowOwner_g)
{
    int bid = blockIdx.x, t = threadIdx.x;
    int k = bid >> 4, r = bid & 15;
    __shared__ int lab[32], rankS[32], luS[32], ownS[128];
    __shared__ int hist[128], redS[128];
    if (t < 32) lab[t] = labels[t];
    if (t < 128) { hist[t] = 0; ownS[t] = -1; }
    __syncthreads();
    if (t < 32) { int rk = 0; for (int j = 0; j < 32; ++j) rk += (lab[j] < lab[t]); rankS[t] = rk; }
    __syncthreads();
    if (t < 32) luS[rankS[t]] = lab[t];
    __syncthreads();
    if (t < 32) ownS[luS[t]] = t;
    __syncthreads();
    int id = 0, isv = 0;
    if (t < 128) {
        id = relIds[((size_t)rankS[k]*NRELD + r)*PSZ + t];
        isv = (id != PSZ);
        if (isv) atomicAdd(&hist[id], 1);
        redS[t] = id + (isv << 20);
    }
    __syncthreads();
    for (int off = 64; off; off >>= 1) {
        if (t < off) redS[t] += redS[t + off];
        __syncthreads();
    }
    int rowsum = redS[0] & 0xFFFFF;
    int cnt    = redS[0] >> 20;
    int rf     = (rowsum > 0);
    if (t < 128)
        S_bf[(size_t)bid*128 + t] = (unsigned short)f2bf(rf ? (float)hist[t] : 0.f);
    if (t == 0) { rowflag[bid] = rf; cntRow[bid] = cnt; }
    if (bid == 0 && t < 128) rowOwner_g[t] = ownS[t];
    if (bid < 128) {
        int p = bid;
        float4 v4 = *(const float4*)&P0[(size_t)p*HID + t*4];
        unsigned int b0 = f2bf(v4.x), b1 = f2bf(v4.y), b2 = f2bf(v4.z), b3 = f2bf(v4.w);
        uint2 d; d.x = b0 | (b1 << 16); d.y = b2 | (b3 << 16);
        *(uint2*)&P0_bf[(size_t)p*HID + t*4] = d;
        P0T_bf[(size_t)(t*4+0)*128 + p] = (unsigned short)b0;
        P0T_bf[(size_t)(t*4+1)*128 + p] = (unsigned short)b1;
        P0T_bf[(size_t)(t*4+2)*128 + p] = (unsigned short)b2;
        P0T_bf[(size_t)(t*4+3)*128 + p] = (unsigned short)b3;
        int kk = ownS[p];
        if (kk >= 0) *(uint2*)&pt_bf[(size_t)kk*HID + t*4] = d;
    }
}

__global__ __launch_bounds__(256) void k_vw(
        const float* __restrict__ rel, const unsigned short* __restrict__ pt_bf,
        const unsigned short* __restrict__ S_bf, const unsigned short* __restrict__ P0T_bf,
        unsigned short* __restrict__ v_bf, unsigned short* __restrict__ w_bf,
        float* __restrict__ prop, float* __restrict__ lossAcc)
{
    __shared__ unsigned short sh[32*768 + 64*128];
    int bid = blockIdx.x, t = threadIdx.x;
    int wave = t >> 6, lane = t & 63;
    if (bid < 192) {
        int r = bid & 15, hs = bid >> 4;
        unsigned short* ptS = sh;
        unsigned short* AS  = sh + 32*768;
        for (int i = t; i < 3072; i += 256) {
            int k = i / 96, c = i % 96;
            uint4 d = *(const uint4*)&pt_bf[(size_t)k*HID + c*8];
            *(uint4*)&ptS[k*768 + (c ^ (k & 7))*8] = d;
        }
        const int gq = (t & 31) * 4;
        const int hr = t >> 5;
        const size_t relbase = ((size_t)r*HID + hs*64) * HID;
        float4 buf[8];
        #pragma unroll
        for (int rr = 0; rr < 8; ++rr)
            buf[rr] = *(const float4*)&rel[relbase + (size_t)(hr + rr*8)*HID + gq];
        f32x4 acc[2] = {{0.f,0.f,0.f,0.f},{0.f,0.f,0.f,0.f}};
        const int arow = wave*16 + (lane & 15);
        for (int gt = 0; gt < 6; ++gt) {
            __syncthreads();
            #pragma unroll
            for (int rr = 0; rr < 8; ++rr) {
                int h_l = hr + rr*8;
                float4 v4 = buf[rr];
                int cs = (gq >> 3) ^ (h_l & 7);
                uint2 d; d.x = f2bf(v4.x) | (f2bf(v4.y) << 16);
                d.y = f2bf(v4.z) | (f2bf(v4.w) << 16);
                *(uint2*)&AS[h_l*128 + cs*8 + (gq & 4)] = d;
            }
            __syncthreads();
            if (gt < 5) {
                int gn = gt*128 + 128;
                #pragma unroll
                for (int rr = 0; rr < 8; ++rr)
                    buf[rr] = *(const float4*)&rel[relbase + (size_t)(hr + rr*8)*HID + gn + gq];
            }
            #pragma unroll
            for (int kk = 0; kk < 4; ++kk) {
                int cA = (kk*4 + (lane >> 4)) ^ (arow & 7);
                bf16x8 a = *(const bf16x8*)&AS[arow*128 + cA*8];
                #pragma unroll
                for (int nf = 0; nf < 2; ++nf) {
                    int k = nf*16 + (lane & 15);
                    int cB = (gt*16 + kk*4 + (lane >> 4)) ^ (k & 7);
                    bf16x8 b = *(const bf16x8*)&ptS[k*768 + cB*8];
                    acc[nf] = __builtin_amdgcn_mfma_f32_16x16x32_bf16(a, b, acc[nf], 0, 0, 0);
                }
            }
        }
        int h_out = hs*64 + wave*16 + (lane >> 4) * 4;
        #pragma unroll
        for (int nf = 0; nf < 2; ++nf) {
            int k = nf*16 + (lane & 15);
            uint2 d; d.x = f2bf(acc[nf][0]) | (f2bf(acc[nf][1]) << 16);
            d.y = f2bf(acc[nf][2]) | (f2bf(acc[nf][3]) << 16);
            *(uint2*)&v_bf[((size_t)k*NRELD + r)*HID + h_out] = d;
        }
    } else {
        int idx = bid - 192;
        int ms = idx / 12, ns = idx % 12;
        unsigned short* AS2 = sh;
        unsigned short* BS2 = sh + 64*128;
        if (t < 64) *(float4*)&prop[idx*256 + t*4] = float4{0.f,0.f,0.f,0.f};
        if (idx == 0 && t == 0) lossAcc[0] = 0.f;
        for (int i = t; i < 1024; i += 256) {
            int row = i >> 4, c = i & 15;
            *(uint4*)&AS2[row*128 + (c ^ (row & 7))*8] =
                *(const uint4*)&S_bf[(size_t)(ms*64 + row)*128 + c*8];
            *(uint4*)&BS2[row*128 + (c ^ (row & 7))*8] =
                *(const uint4*)&P0T_bf[(size_t)(ns*64 + row)*128 + c*8];
        }
        __syncthreads();
        f32x4 acc[4] = {{0.f,0.f,0.f,0.f},{0.f,0.f,0.f,0.f},{0.f,0.f,0.f,0.f},{0.f,0.f,0.f,0.f}};
        int arow = wave*16 + (lane & 15);
        #pragma unroll
        for (int kk = 0; kk < 4; ++kk) {
            int cA = (kk*4 + (lane >> 4)) ^ (arow & 7);
            bf16x8 a = *(const bf16x8*)&AS2[arow*128 + cA*8];
            #pragma unroll
            for (int nf = 0; nf < 4; ++nf) {
                int brow = nf*16 + (lane & 15);
                int cB = (kk*4 + (lane >> 4)) ^ (brow & 7);
                bf16x8 b = *(const bf16x8*)&BS2[brow*128 + cB*8];
                acc[nf] = __builtin_amdgcn_mfma_f32_16x16x32_bf16(a, b, acc[nf], 0, 0, 0);
            }
        }
        int kr0 = ms*64 + wave*16 + (lane >> 4) * 4;
        #pragma unroll
        for (int nf = 0; nf < 4; ++nf) {
            int h = ns*64 + nf*16 + (lane & 15);
            #pragma unroll
            for (int j = 0; j < 4; ++j)
                w_bf[(size_t)(kr0 + j)*HID + h] = (unsigned short)f2bf(acc[nf][j]);
        }
    }
}

__global__ __launch_bounds__(256) void k_prop_mfma(
        const float* __restrict__ rel, const unsigned short* __restrict__ w_bf,
        float* __restrict__ prop)
{
    int r = blockIdx.x, gs = blockIdx.y, t = threadIdx.x;
    int wave = t >> 6, lane = t & 63;
    __shared__ unsigned short WS[32*768];
    __shared__ unsigned short BS[64*128];
    for (int i = t; i < 3072; i += 256) {
        int k = i / 96, c = i % 96;
        uint4 d = *(const uint4*)&w_bf[((size_t)k*NRELD + r)*HID + c*8];
        *(uint4*)&WS[k*768 + (c ^ (k & 7))*8] = d;
    }
    const int gqq = t & 15;
    const int h4  = t >> 4;
    const size_t relb = (size_t)r*HID*HID + (size_t)gs*64;
    float4 buf[8];
    #pragma unroll
    for (int sup = 0; sup < 2; ++sup)
        #pragma unroll
        for (int rr = 0; rr < 4; ++rr)
            buf[sup*4+rr] = *(const float4*)&rel[relb + (size_t)(sup*64 + h4*4 + rr)*HID + gqq*4];
    f32x4 acc[2] = {{0.f,0.f,0.f,0.f},{0.f,0.f,0.f,0.f}};
    for (int ht = 0; ht < 6; ++ht) {
        __syncthreads();
        #pragma unroll
        for (int sup = 0; sup < 2; ++sup) {
            #pragma unroll
            for (int i = 0; i < 4; ++i) {
                int g_l = gqq*4 + i;
                int hloc = sup*64 + h4*4;
                unsigned int p0 = f2bf(((const float*)&buf[sup*4+0])[i]);
                unsigned int p1 = f2bf(((const float*)&buf[sup*4+1])[i]);
                unsigned int p2 = f2bf(((const float*)&buf[sup*4+2])[i]);
                unsigned int p3 = f2bf(((const float*)&buf[sup*4+3])[i]);
                int cs = (hloc >> 3) ^ ((g_l >> 2) & 7);
                uint2 d; d.x = p0 | (p1 << 16); d.y = p2 | (p3 << 16);
                *(uint2*)&BS[g_l*128 + cs*8 + (hloc & 4)] = d;
            }
        }
        __syncthreads();
        if (ht < 5) {
            int hn = ht*128 + 128;
            #pragma unroll
            for (int sup = 0; sup < 2; ++sup)
                #pragma unroll
                for (int rr = 0; rr < 4; ++rr)
                    buf[sup*4+rr] = *(const float4*)&rel[relb + (size_t)(hn + sup*64 + h4*4 + rr)*HID + gqq*4];
        }
        int g_l = wave*16 + (lane & 15);
        #pragma unroll
        for (int kk = 0; kk < 4; ++kk) {
            int cB = (kk*4 + (lane >> 4)) ^ ((g_l >> 2) & 7);
            bf16x8 b = *(const bf16x8*)&BS[g_l*128 + cB*8];
            #pragma unroll
            for (int mf = 0; mf < 2; ++mf) {
                int arow = mf*16 + (lane & 15);
                int cA = (ht*16 + kk*4 + (lane >> 4)) ^ (arow & 7);
                bf16x8 a = *(const bf16x8*)&WS[arow*768 + cA*8];
                acc[mf] = __builtin_amdgcn_mfma_f32_16x16x32_bf16(a, b, acc[mf], 0, 0, 0);
            }
        }
    }
    int gcol = gs*64 + wave*16 + (lane & 15);
    #pragma unroll
    for (int mf = 0; mf < 2; ++mf) {
        int k0 = mf*16 + (lane >> 4) * 4;
        #pragma unroll
        for (int j = 0; j < 4; ++j)
            atomicAdd(&prop[(size_t)(k0 + j)*HID + gcol], acc[mf][j]);
    }
}

__global__ __launch_bounds__(256) void k_zzproto(
        const unsigned short* __restrict__ v_bf, const unsigned short* __restrict__ P0_bf,
        const unsigned short* __restrict__ S_bf, float* __restrict__ lossAcc,
        const float* __restrict__ P0, const float* __restrict__ prop,
        const int* __restrict__ rowflag, const int* __restrict__ cntRow,
        const int* __restrict__ rowOwner_g, float* __restrict__ protoOut)
{
    __shared__ unsigned short sh[16*128 + 128*128];
    __shared__ float red[256];
    __shared__ float nActS[32];
    __shared__ int kS[32];
    int bid = blockIdx.x, t = threadIdx.x;
    int wave = t >> 6, lane = t & 63;
    if (bid < 32) {
        int ms = bid;
        unsigned short* AS  = sh;
        unsigned short* BS2 = sh + 16*128;
        f32x4 acc[2] = {{0.f,0.f,0.f,0.f},{0.f,0.f,0.f,0.f}};
        for (int ht = 0; ht < 6; ++ht) {
            int h0 = ht * 128;
            __syncthreads();
            {
                int row = t >> 4, c = t & 15;
                *(uint4*)&AS[row*128 + (c ^ (row & 7))*8] =
                    *(const uint4*)&v_bf[(size_t)(ms*16 + row)*HID + h0 + c*8];
                #pragma unroll
                for (int q = 0; q < 8; ++q) {
                    int j2 = t + q*256;
                    int prow = j2 >> 4, c2 = j2 & 15;
                    *(uint4*)&BS2[prow*128 + (c2 ^ (prow & 7))*8] =
                        *(const uint4*)&P0_bf[(size_t)prow*HID + h0 + c2*8];
                }
            }
            __syncthreads();
            int arow = lane & 15;
            #pragma unroll
            for (int kk = 0; kk < 4; ++kk) {
                int cA = (kk*4 + (lane >> 4)) ^ (arow & 7);
                bf16x8 a = *(const bf16x8*)&AS[arow*128 + cA*8];
                #pragma unroll
                for (int nf = 0; nf < 2; ++nf) {
                    int brow = wave*32 + nf*16 + (lane & 15);
                    int cB = (kk*4 + (lane >> 4)) ^ (brow & 7);
                    bf16x8 b = *(const bf16x8*)&BS2[brow*128 + cB*8];
                    acc[nf] = __builtin_amdgcn_mfma_f32_16x16x32_bf16(a, b, acc[nf], 0, 0, 0);
                }
            }
        }
        float term = 0.f;
        #pragma unroll
        for (int nf = 0; nf < 2; ++nf) {
            int p = wave*32 + nf*16 + (lane & 15);
            int kr0 = ms*16 + (lane >> 4) * 4;
            #pragma unroll
            for (int j = 0; j < 4; ++j) {
                float S = bf2f(S_bf[(size_t)(kr0 + j)*128 + p]);
                if (S != 0.f) {
                    float z = acc[nf][j];
                    float s = 1.f / (1.f + expf(-z));
                    term += S * (logf(expf(1.f - s) + expf(s)) - s);
                }
            }
        }
        red[t] = term;
        __syncthreads();
        for (int off = 128; off; off >>= 1) {
            if (t < off) red[t] += red[t + off];
            __syncthreads();
        }
        if (t == 0) atomicAdd(lossAcc, red[0]);
    } else {
        int base = (bid - 32) * 32;
        if (t < 32) {
            int p = base + t;
            int k = rowOwner_g[p];
            float n = 0.f;
            if (k >= 0)
                for (int i = 0; i < 16; ++i) {
                    int rr = k*NRELD + i;
                    if (rowflag[rr]) n += (float)cntRow[rr];
                }
            nActS[t] = n; kS[t] = k;
        }
        __syncthreads();
        for (int j = 0; j < 24; ++j) {
            int flat = t + 256*j;
            int pl = flat / 192, c = flat % 192;
            int p = base + pl;
            float4 old = *(const float4*)&P0[(size_t)p*HID + c*4];
            float4 o = old;
            int k = kS[pl]; float n = nActS[pl];
            if (k >= 0 && n > 0.f) {
                float4 pr = *(const float4*)&prop[(size_t)k*HID + c*4];
                float invn = 0.5f / n;
                o.x = 0.5f*old.x + pr.x*invn;
                o.y = 0.5f*old.y + pr.y*invn;
                o.z = 0.5f*old.z + pr.z*invn;
                o.w = 0.5f*old.w + pr.w*invn;
            }
            *(float4*)&protoOut[(size_t)p*HID + c*4] = o;
        }
    }
}

__global__ __launch_bounds__(128) void k_logits(const float* __restrict__ inst,
        const float* __restrict__ protoOut, const float* __restrict__ lossAcc,
        const int* __restrict__ rowflag, const int* __restrict__ cntRow,
        float* __restrict__ outLogits, float* __restrict__ outLoss)
{
    int b = blockIdx.x, t = threadIdx.x;
    __shared__ float iS[768];
    __shared__ float ls[128];
    __shared__ int ts[128];
    for (int q = 0; q < 6; ++q) iS[t + 128*q] = inst[(size_t)b*HID + t + 128*q];
    __syncthreads();
    const float4* pr = (const float4*)&protoOut[(size_t)t*HID];
    float acc = 0.f;
    for (int q = 0; q < HID/4; ++q) {
        float4 pv = pr[q];
        float dx = iS[q*4+0] - pv.x, dy = iS[q*4+1] - pv.y;
        float dz = iS[q*4+2] - pv.z, dw = iS[q*4+3] - pv.w;
        acc += dx*dx + dy*dy + dz*dz + dw*dw;
    }
    outLogits[b*PSZ + t] = -acc;
    if (b == 0) {
        float s = 0.f; int tot = 0;
        #pragma unroll
        for (int q = 0; q < 4; ++q) {
            int rr = t + 128*q;
            int rf = rowflag[rr];
            tot |= rf;
            if (rf) s += (float)cntRow[rr];
        }
        ls[t] = s; ts[t] = tot;
        __syncthreads();
        for (int off = 64; off; off >>= 1) {
            if (t < off) { ls[t] += ls[t + off]; ts[t] |= ts[t + off]; }
            __syncthreads();
        }
        if (t == 0)
            outLoss[0] = ts[0]
                ? (lossAcc[0] + (65536.f - ls[0]) * 0.6931471805599453f) * (1.f/65536.f)
                : 0.f;
    }
}

// -------------------------------------------------------------------------
extern "C" void kernel_launch(void* const* d_in, const int* in_sizes, int n_in,
                              void* d_out, int out_size, void* d_ws, size_t ws_size,
                              hipStream_t stream)
{
    const float* inst  = (const float*)d_in[0];   // [32,768]
    const float* rel   = (const float*)d_in[1];   // [16,768,768]
    const int* relIds  = (const int*)d_in[2];     // [32,16,128]
    const int* labels  = (const int*)d_in[3];     // [32]
    const float* P0    = (const float*)d_in[4];   // [128,768]
    float* out = (float*)d_out;
    float* outLogits = out;            // 4096
    float* outLoss   = out + 4096;     // 1
    float* outProto  = out + 4097;     // 98304

    char* ws = (char*)d_ws;
    unsigned short* v_bf    = (unsigned short*)(ws + 0);        // 786432 B
    unsigned short* w_bf    = (unsigned short*)(ws + 786432);   // 786432 B
    unsigned short* S_bf    = (unsigned short*)(ws + 1572864);  // 131072 B
    unsigned short* P0_bf   = (unsigned short*)(ws + 1703936);  // 196608 B
    unsigned short* P0T_bf  = (unsigned short*)(ws + 1900544);  // 196608 B
    unsigned short* pt_bf   = (unsigned short*)(ws + 2097152);  // 49152 B
    float* prop    = (float*)(ws + 2146304);                    // 98304 B
    float* lossAcc = (float*)(ws + 2244608);                    // 128 B
    int*   rowflag = (int*)(ws + 2244736);                      // 2048 B
    int*   cntRow  = (int*)(ws + 2246784);                      // 2048 B
    int*   rowOwner= (int*)(ws + 2248832);                      // 512 B

    MegaParams Pm;
    Pm.inst = inst; Pm.rel = rel; Pm.relIds = relIds; Pm.labels = labels; Pm.P0 = P0;
    Pm.S_bf = S_bf; Pm.P0_bf = P0_bf; Pm.P0T_bf = P0T_bf; Pm.pt_bf = pt_bf;
    Pm.v_bf = v_bf; Pm.w_bf = w_bf; Pm.prop = prop; Pm.lossAcc = lossAcc;
    Pm.rowflag = rowflag; Pm.cntRow = cntRow;
    Pm.outLogits = outLogits; Pm.outLoss = outLoss; Pm.outProto = outProto;

    void* args[] = { &Pm };
    hipError_t err = hipLaunchCooperativeKernel((const void*)k_mega,
                                                dim3(288), dim3(256),
                                                args, 0, stream);
    if (err != hipSuccess) {
        // Fallback: proven 5-kernel path
        k_prep<<<512, 192, 0, stream>>>(labels, relIds, P0, S_bf, P0_bf, P0T_bf,
                                        pt_bf, rowflag, cntRow, rowOwner);
        k_vw<<<288, 256, 0, stream>>>(rel, pt_bf, S_bf, P0T_bf, v_bf, w_bf,
                                      prop, lossAcc);
        k_prop_mfma<<<dim3(16,12), 256, 0, stream>>>(rel, w_bf, prop);
        k_zzproto<<<36, 256, 0, stream>>>(v_bf, P0_bf, S_bf, lossAcc, P0, prop,
                                          rowflag, cntRow, rowOwner, outProto);
        k_logits<<<32, 128, 0, stream>>>(inst, outProto, lossAcc, rowflag, cntRow,
                                         outLogits, outLoss);
    }
}

// Round 5
// 157.166 us; speedup vs baseline: 1.5923x; 1.5923x over previous
//
#include <hip/hip_runtime.h>
#include <hip/hip_bf16.h>
#include <math.h>

#define K_B 32
#define NRELD 16
#define PSZ 128
#define HID 768

using bf16x8 = __attribute__((ext_vector_type(8))) short;
using f32x4  = __attribute__((ext_vector_type(4))) float;

__device__ __forceinline__ unsigned int f2bf(float x) {   // fp32 -> bf16 bits (RNE)
    unsigned int u = __float_as_uint(x);
    return (u + 0x7fffu + ((u >> 16) & 1u)) >> 16;
}
__device__ __forceinline__ float bf2f(unsigned short b) {
    return __uint_as_float(((unsigned int)b) << 16);
}

// =========================================================================
// L1: 768 blocks x 192 thr
//   bid <  512 : per-(k,r) masks + gated S histogram + gather-sum w row
//   bid <  640 : P0 -> P0_bf, pt_bf conversions
//   bid >= 640 : zero v_f32 / prop / lossAcc / done
// =========================================================================
__global__ __launch_bounds__(192) void k_prep(
        const int* __restrict__ labels, const int* __restrict__ relIds,
        const float* __restrict__ P0,
        unsigned short* __restrict__ S_bf, unsigned short* __restrict__ P0_bf,
        unsigned short* __restrict__ pt_bf, unsigned short* __restrict__ w_bf,
        int* __restrict__ rowflag, int* __restrict__ cntRow,
        float* __restrict__ v_f32, float* __restrict__ prop,
        float* __restrict__ lossAcc, int* __restrict__ done)
{
    const int bid = blockIdx.x, t = threadIdx.x;
    __shared__ int lab[32], rankS[32], luS[32], ownS[128];
    __shared__ int ids[128], hist[128], redS[192];
    if (t < 32) lab[t] = labels[t];
    if (t < 128) { ownS[t] = -1; hist[t] = 0; }
    redS[t] = 0;
    __syncthreads();
    if (t < 32) { int rk = 0; for (int j = 0; j < 32; ++j) rk += (lab[j] < lab[t]); rankS[t] = rk; }
    __syncthreads();
    if (t < 32) luS[rankS[t]] = lab[t];
    __syncthreads();
    if (t < 32) ownS[luS[t]] = t;
    __syncthreads();

    if (bid < 512) {
        int k = bid >> 4, r = bid & 15;
        int id = PSZ, isv = 0;
        if (t < 128) {
            id = relIds[((size_t)rankS[k]*NRELD + r)*PSZ + t];
            ids[t] = id;
            isv = (id != PSZ);
            if (isv) atomicAdd(&hist[id], 1);
            redS[t] = id + (isv << 20);      // raw rowsum | cnt<<20
        }
        __syncthreads();
        for (int off = 64; off; off >>= 1) {
            if (t < off) redS[t] += redS[t + off];
            __syncthreads();
        }
        int rf  = ((redS[0] & 0xFFFFF) > 0);
        int cnt = redS[0] >> 20;
        if (t < 128) S_bf[(size_t)bid*128 + t] = (unsigned short)f2bf(rf ? (float)hist[t] : 0.f);
        if (t == 0) { rowflag[bid] = rf; cntRow[bid] = cnt; }
        // gather-sum w row (f32, gated)
        float4 acc = {0.f, 0.f, 0.f, 0.f};
        if (rf) {
            for (int j = 0; j < 128; ++j) {
                int idj = ids[j];                        // LDS scalar, wave-uniform
                if (idj != PSZ) {
                    float4 pv = *(const float4*)&P0[(size_t)idj*HID + t*4];
                    acc.x += pv.x; acc.y += pv.y; acc.z += pv.z; acc.w += pv.w;
                }
            }
        }
        uint2 d; d.x = f2bf(acc.x) | (f2bf(acc.y) << 16);
        d.y = f2bf(acc.z) | (f2bf(acc.w) << 16);
        *(uint2*)&w_bf[(size_t)bid*HID + t*4] = d;
    } else if (bid < 640) {
        int p = bid - 512;
        float4 v4 = *(const float4*)&P0[(size_t)p*HID + t*4];
        unsigned int b0 = f2bf(v4.x), b1 = f2bf(v4.y), b2 = f2bf(v4.z), b3 = f2bf(v4.w);
        uint2 d; d.x = b0 | (b1 << 16); d.y = b2 | (b3 << 16);
        *(uint2*)&P0_bf[(size_t)p*HID + t*4] = d;
        int kk = ownS[p];
        if (kk >= 0) *(uint2*)&pt_bf[(size_t)kk*HID + t*4] = d;
    } else {
        int idx = bid - 640;                 // 0..127
        float4 z = {0.f, 0.f, 0.f, 0.f};
        float4* v4p = (float4*)v_f32;
        #pragma unroll
        for (int q = 0; q < 4; ++q) v4p[idx*768 + q*192 + t] = z;
        float4* p4p = (float4*)prop;
        if (t < 48) p4p[idx*48 + t] = z;
        if (idx == 0 && t == 0) { lossAcc[0] = 0.f; done[0] = 0; }
    }
}

// =========================================================================
// L2: 768 blocks x 256 thr, 16 KB LDS
//   bid < 384 : v partial GEMM  v[h,k] += Rel_r[h-slab, g-half] x pt^T
//   bid >=384 : prop partial    prop[k,g] += W_r[k, h-half] x Rel_r[h,g-slab]
// MFMA partner fragments (pt_bf / w_bf) read directly from global (L2).
// =========================================================================
__global__ __launch_bounds__(256) void k_vprop(
        const float* __restrict__ rel, const unsigned short* __restrict__ pt_bf,
        const unsigned short* __restrict__ w_bf,
        float* __restrict__ v_f32, float* __restrict__ prop)
{
    __shared__ unsigned short sh[64*128];    // 16 KB tile
    const int bid = blockIdx.x, t = threadIdx.x;
    const int wave = t >> 6, lane = t & 63;

    if (bid < 384) {
        // ---- v role ----
        int gh = bid / 192, rest = bid % 192;
        int hs = rest >> 4, r = rest & 15;
        unsigned short* AS = sh;             // [64 h][128 g], chunk c^=(h&7)
        const int gq = (t & 31) * 4;
        const int hr = t >> 5;
        const size_t relbase = ((size_t)r*HID + hs*64)*HID + gh*384;

        float4 buf[8];
        #pragma unroll
        for (int rr = 0; rr < 8; ++rr)
            buf[rr] = *(const float4*)&rel[relbase + (size_t)(hr + rr*8)*HID + gq];

        f32x4 acc[2] = {{0.f,0.f,0.f,0.f},{0.f,0.f,0.f,0.f}};
        const int arow = wave*16 + (lane & 15);

        for (int gt = 0; gt < 3; ++gt) {
            __syncthreads();
            #pragma unroll
            for (int rr = 0; rr < 8; ++rr) {
                int h_l = hr + rr*8;
                float4 v4 = buf[rr];
                int cs = (gq >> 3) ^ (h_l & 7);
                uint2 d; d.x = f2bf(v4.x) | (f2bf(v4.y) << 16);
                d.y = f2bf(v4.z) | (f2bf(v4.w) << 16);
                *(uint2*)&AS[h_l*128 + cs*8 + (gq & 4)] = d;
            }
            __syncthreads();
            if (gt < 2) {
                int gn = gt*128 + 128;
                #pragma unroll
                for (int rr = 0; rr < 8; ++rr)
                    buf[rr] = *(const float4*)&rel[relbase + (size_t)(hr + rr*8)*HID + gn + gq];
            }
            #pragma unroll
            for (int kk = 0; kk < 4; ++kk) {
                int cA = (kk*4 + (lane >> 4)) ^ (arow & 7);
                bf16x8 a = *(const bf16x8*)&AS[arow*128 + cA*8];
                #pragma unroll
                for (int nf = 0; nf < 2; ++nf) {
                    int k = nf*16 + (lane & 15);
                    bf16x8 b = *(const bf16x8*)&pt_bf[(size_t)k*HID + gh*384 + gt*128 + kk*32 + (lane >> 4)*8];
                    acc[nf] = __builtin_amdgcn_mfma_f32_16x16x32_bf16(a, b, acc[nf], 0, 0, 0);
                }
            }
        }
        int h_out = hs*64 + wave*16 + (lane >> 4)*4;
        #pragma unroll
        for (int nf = 0; nf < 2; ++nf) {
            int k = nf*16 + (lane & 15);
            #pragma unroll
            for (int j = 0; j < 4; ++j)
                atomicAdd(&v_f32[((size_t)k*NRELD + r)*HID + h_out + j], acc[nf][j]);
        }
    } else {
        // ---- prop role ----
        int idx = bid - 384;
        int hh = idx / 192, rest = idx % 192;
        int gs = rest >> 4, r = rest & 15;
        unsigned short* BS = sh;             // [64 g][128 h], chunk c^=((g>>2)&7)
        const int gqq = t & 15;
        const int h4  = t >> 4;
        const size_t relb = (size_t)r*HID*HID + (size_t)gs*64 + (size_t)hh*384*HID;

        float4 buf[8];
        #pragma unroll
        for (int sup = 0; sup < 2; ++sup)
            #pragma unroll
            for (int rr = 0; rr < 4; ++rr)
                buf[sup*4+rr] = *(const float4*)&rel[relb + (size_t)(sup*64 + h4*4 + rr)*HID + gqq*4];

        f32x4 acc[2] = {{0.f,0.f,0.f,0.f},{0.f,0.f,0.f,0.f}};

        for (int ht = 0; ht < 3; ++ht) {
            __syncthreads();
            #pragma unroll
            for (int sup = 0; sup < 2; ++sup) {
                #pragma unroll
                for (int i = 0; i < 4; ++i) {
                    int g_l = gqq*4 + i;
                    int hloc = sup*64 + h4*4;
                    unsigned int p0 = f2bf(((const float*)&buf[sup*4+0])[i]);
                    unsigned int p1 = f2bf(((const float*)&buf[sup*4+1])[i]);
                    unsigned int p2 = f2bf(((const float*)&buf[sup*4+2])[i]);
                    unsigned int p3 = f2bf(((const float*)&buf[sup*4+3])[i]);
                    int cs = (hloc >> 3) ^ ((g_l >> 2) & 7);
                    uint2 d; d.x = p0 | (p1 << 16); d.y = p2 | (p3 << 16);
                    *(uint2*)&BS[g_l*128 + cs*8 + (hloc & 4)] = d;
                }
            }
            __syncthreads();
            if (ht < 2) {
                int hn = ht*128 + 128;
                #pragma unroll
                for (int sup = 0; sup < 2; ++sup)
                    #pragma unroll
                    for (int rr = 0; rr < 4; ++rr)
                        buf[sup*4+rr] = *(const float4*)&rel[relb + (size_t)(hn + sup*64 + h4*4 + rr)*HID + gqq*4];
            }
            int g_l = wave*16 + (lane & 15);
            #pragma unroll
            for (int kk = 0; kk < 4; ++kk) {
                int cB = (kk*4 + (lane >> 4)) ^ ((g_l >> 2) & 7);
                bf16x8 b = *(const bf16x8*)&BS[g_l*128 + cB*8];
                #pragma unroll
                for (int mf = 0; mf < 2; ++mf) {
                    int arow = mf*16 + (lane & 15);
                    bf16x8 a = *(const bf16x8*)&w_bf[((size_t)arow*NRELD + r)*HID + hh*384 + ht*128 + kk*32 + (lane >> 4)*8];
                    acc[mf] = __builtin_amdgcn_mfma_f32_16x16x32_bf16(a, b, acc[mf], 0, 0, 0);
                }
            }
        }
        int gcol = gs*64 + wave*16 + (lane & 15);
        #pragma unroll
        for (int mf = 0; mf < 2; ++mf) {
            int k0 = mf*16 + (lane >> 4)*4;
            #pragma unroll
            for (int j = 0; j < 4; ++j)
                atomicAdd(&prop[(size_t)(k0 + j)*HID + gcol], acc[mf][j]);
        }
    }
}

// =========================================================================
// L3: 40 blocks x 256 thr
//   bid < 32 : zz GEMM + CE loss; last-done block finalizes outLoss
//   bid >=32 : proto scatter-update + logits (16 p-rows / block)
// =========================================================================
__global__ __launch_bounds__(256) void k_tail(
        const float* __restrict__ v_f32, const unsigned short* __restrict__ P0_bf,
        const unsigned short* __restrict__ S_bf, float* __restrict__ lossAcc,
        int* __restrict__ done,
        const float* __restrict__ P0, const float* __restrict__ prop,
        const int* __restrict__ rowflag, const int* __restrict__ cntRow,
        const int* __restrict__ labels, const float* __restrict__ inst,
        float* __restrict__ outProto, float* __restrict__ outLogits,
        float* __restrict__ outLoss)
{
    __shared__ __align__(16) char shraw[16*772*4];    // 49408 B union
    __shared__ int lab[32], rankS[32], luS[32], ownS[128];
    __shared__ float redF[256];
    __shared__ int redI[256];
    __shared__ float nActS[16];
    __shared__ int kS2[16];
    const int bid = blockIdx.x, t = threadIdx.x;
    const int wave = t >> 6, lane = t & 63;

    if (t < 32) lab[t] = labels[t];
    if (t < 128) ownS[t] = -1;
    __syncthreads();
    if (t < 32) { int rk = 0; for (int j = 0; j < 32; ++j) rk += (lab[j] < lab[t]); rankS[t] = rk; }
    __syncthreads();
    if (t < 32) luS[rankS[t]] = lab[t];
    __syncthreads();
    if (t < 32) ownS[luS[t]] = t;
    __syncthreads();

    if (bid < 32) {
        // ---- zz + CE loss ----
        int ms = bid;
        unsigned short* AS  = (unsigned short*)shraw;            // 16x128 bf16
        unsigned short* BS2 = (unsigned short*)shraw + 16*128;   // 128x128 bf16
        f32x4 acc[2] = {{0.f,0.f,0.f,0.f},{0.f,0.f,0.f,0.f}};
        for (int ht = 0; ht < 6; ++ht) {
            int h0 = ht * 128;
            __syncthreads();
            {
                int row = t >> 4, c = t & 15;
                const float* vp = &v_f32[(size_t)(ms*16 + row)*HID + h0 + c*8];
                float4 a0 = *(const float4*)vp;
                float4 a1 = *(const float4*)(vp + 4);
                uint4 d;
                d.x = f2bf(a0.x) | (f2bf(a0.y) << 16);
                d.y = f2bf(a0.z) | (f2bf(a0.w) << 16);
                d.z = f2bf(a1.x) | (f2bf(a1.y) << 16);
                d.w = f2bf(a1.z) | (f2bf(a1.w) << 16);
                *(uint4*)&AS[row*128 + (c ^ (row & 7))*8] = d;
                #pragma unroll
                for (int q = 0; q < 8; ++q) {
                    int j2 = t + q*256;
                    int prow = j2 >> 4, c2 = j2 & 15;
                    *(uint4*)&BS2[prow*128 + (c2 ^ (prow & 7))*8] =
                        *(const uint4*)&P0_bf[(size_t)prow*HID + h0 + c2*8];
                }
            }
            __syncthreads();
            int arow = lane & 15;
            #pragma unroll
            for (int kk = 0; kk < 4; ++kk) {
                int cA = (kk*4 + (lane >> 4)) ^ (arow & 7);
                bf16x8 a = *(const bf16x8*)&AS[arow*128 + cA*8];
                #pragma unroll
                for (int nf = 0; nf < 2; ++nf) {
                    int brow = wave*32 + nf*16 + (lane & 15);
                    int cB = (kk*4 + (lane >> 4)) ^ (brow & 7);
                    bf16x8 b = *(const bf16x8*)&BS2[brow*128 + cB*8];
                    acc[nf] = __builtin_amdgcn_mfma_f32_16x16x32_bf16(a, b, acc[nf], 0, 0, 0);
                }
            }
        }
        float term = 0.f;
        #pragma unroll
        for (int nf = 0; nf < 2; ++nf) {
            int p = wave*32 + nf*16 + (lane & 15);
            int kr0 = ms*16 + (lane >> 4)*4;
            #pragma unroll
            for (int j = 0; j < 4; ++j) {
                float S = bf2f(S_bf[(size_t)(kr0 + j)*128 + p]);
                if (S != 0.f) {
                    float z = acc[nf][j];
                    float s = 1.f / (1.f + expf(-z));
                    term += S * (logf(expf(1.f - s) + expf(s)) - s);
                }
            }
        }
        redF[t] = term;
        __syncthreads();
        for (int off = 128; off; off >>= 1) {
            if (t < off) redF[t] += redF[t + off];
            __syncthreads();
        }
        if (t == 0) atomicAdd(lossAcc, redF[0]);
        __threadfence();
        __syncthreads();
        float s2 = 0.f; int tot = 0;
        #pragma unroll
        for (int q = 0; q < 2; ++q) {
            int rr2 = t + 256*q;
            int rf = rowflag[rr2];
            tot |= rf;
            if (rf) s2 += (float)cntRow[rr2];
        }
        redF[t] = s2; redI[t] = tot;
        __syncthreads();
        for (int off = 128; off; off >>= 1) {
            if (t < off) { redF[t] += redF[t + off]; redI[t] |= redI[t + off]; }
            __syncthreads();
        }
        if (t == 0) {
            int old = atomicAdd(done, 1);
            if (old == 31) {
                __threadfence();
                float cur = atomicAdd(lossAcc, 0.f);   // atomic read of final sum
                outLoss[0] = redI[0]
                    ? (cur + (65536.f - redF[0]) * 0.6931471805599453f) * (1.f/65536.f)
                    : 0.f;
            }
        }
    } else {
        // ---- proto update + logits, 16 p-rows per block ----
        float* protoS = (float*)shraw;       // [16][772] padded
        const int PSTR = 772;
        int pb = (bid - 32) * 16;
        if (t < 16) {
            int p = pb + t;
            int k = ownS[p];
            float n = 0.f;
            if (k >= 0)
                for (int i = 0; i < 16; ++i) {
                    int rr2 = k*NRELD + i;
                    if (rowflag[rr2]) n += (float)cntRow[rr2];
                }
            nActS[t] = n; kS2[t] = k;
        }
        __syncthreads();
        for (int it = t; it < 16*192; it += 256) {
            int pl = it / 192, c = it % 192;
            int p = pb + pl;
            float4 old = *(const float4*)&P0[(size_t)p*HID + c*4];
            float4 o = old;
            int k = kS2[pl]; float n = nActS[pl];
            if (k >= 0 && n > 0.f) {
                float4 pr = *(const float4*)&prop[(size_t)k*HID + c*4];
                float invn = 0.5f / n;
                o.x = 0.5f*old.x + pr.x*invn;
                o.y = 0.5f*old.y + pr.y*invn;
                o.z = 0.5f*old.z + pr.z*invn;
                o.w = 0.5f*old.w + pr.w*invn;
            }
            *(float4*)&outProto[(size_t)p*HID + c*4] = o;
            protoS[pl*PSTR + c*4+0] = o.x;
            protoS[pl*PSTR + c*4+1] = o.y;
            protoS[pl*PSTR + c*4+2] = o.z;
            protoS[pl*PSTR + c*4+3] = o.w;
        }
        __syncthreads();
        int b = t & 31, p2 = (t >> 5) * 2;
        const float4* ir = (const float4*)&inst[(size_t)b*HID];
        float a0 = 0.f, a1 = 0.f;
        for (int q = 0; q < HID/4; ++q) {
            float4 iv = ir[q];
            float4 pv0 = *(const float4*)&protoS[p2*PSTR + q*4];
            float4 pv1 = *(const float4*)&protoS[(p2+1)*PSTR + q*4];
            float dx = iv.x - pv0.x, dy = iv.y - pv0.y, dz = iv.z - pv0.z, dw = iv.w - pv0.w;
            a0 += dx*dx + dy*dy + dz*dz + dw*dw;
            dx = iv.x - pv1.x; dy = iv.y - pv1.y; dz = iv.z - pv1.z; dw = iv.w - pv1.w;
            a1 += dx*dx + dy*dy + dz*dz + dw*dw;
        }
        outLogits[b*PSZ + pb + p2]     = -a0;
        outLogits[b*PSZ + pb + p2 + 1] = -a1;
    }
}

// -------------------------------------------------------------------------
extern "C" void kernel_launch(void* const* d_in, const int* in_sizes, int n_in,
                              void* d_out, int out_size, void* d_ws, size_t ws_size,
                              hipStream_t stream)
{
    const float* inst  = (const float*)d_in[0];   // [32,768]
    const float* rel   = (const float*)d_in[1];   // [16,768,768]
    const int* relIds  = (const int*)d_in[2];     // [32,16,128]
    const int* labels  = (const int*)d_in[3];     // [32]
    const float* P0    = (const float*)d_in[4];   // [128,768]
    float* out = (float*)d_out;
    float* outLogits = out;            // 4096
    float* outLoss   = out + 4096;     // 1
    float* outProto  = out + 4097;     // 98304

    char* ws = (char*)d_ws;
    float* v_f32            = (float*)(ws + 0);                 // 1572864 B
    unsigned short* w_bf    = (unsigned short*)(ws + 1572864);  // 786432 B
    unsigned short* S_bf    = (unsigned short*)(ws + 2359296);  // 131072 B
    unsigned short* P0_bf   = (unsigned short*)(ws + 2490368);  // 196608 B
    unsigned short* pt_bf   = (unsigned short*)(ws + 2686976);  // 49152 B
    float* prop    = (float*)(ws + 2736128);                    // 98304 B
    float* lossAcc = (float*)(ws + 2834432);                    // 128 B
    int*   done    = (int*)(ws + 2834560);                      // 128 B
    int*   rowflag = (int*)(ws + 2834688);                      // 2048 B
    int*   cntRow  = (int*)(ws + 2836736);                      // 2048 B

    k_prep<<<768, 192, 0, stream>>>(labels, relIds, P0, S_bf, P0_bf, pt_bf,
                                    w_bf, rowflag, cntRow, v_f32, prop,
                                    lossAcc, done);
    k_vprop<<<768, 256, 0, stream>>>(rel, pt_bf, w_bf, v_f32, prop);
    k_tail<<<40, 256, 0, stream>>>(v_f32, P0_bf, S_bf, lossAcc, done, P0, prop,
                                   rowflag, cntRow, labels, inst,
                                   outProto, outLogits, outLoss);
}

// Round 6
// 137.040 us; speedup vs baseline: 1.8262x; 1.1469x over previous
//
#include <hip/hip_runtime.h>
#include <hip/hip_bf16.h>
#include <math.h>

#define K_B 32
#define NRELD 16
#define PSZ 128
#define HID 768

using bf16x8 = __attribute__((ext_vector_type(8))) short;
using f32x4  = __attribute__((ext_vector_type(4))) float;

__device__ __forceinline__ unsigned int f2bf(float x) {   // fp32 -> bf16 bits (RNE)
    unsigned int u = __float_as_uint(x);
    return (u + 0x7fffu + ((u >> 16) & 1u)) >> 16;
}
__device__ __forceinline__ float bf2f(unsigned short b) {
    return __uint_as_float(((unsigned int)b) << 16);
}

// -------------------------------------------------------------------------
// K1 (k_prep): per-(k,r) gated histogram S + rowflag/cntRow; blocks<128
// also convert P0 (P0_bf, P0T_bf, pt_bf). Block 0 zeroes done.
// grid 512 (k*16+r), 192 thr   [R3-verbatim + done zero]
// -------------------------------------------------------------------------
__global__ __launch_bounds__(192) void k_prep(
        const int* __restrict__ labels, const int* __restrict__ relIds,
        const float* __restrict__ P0,
        unsigned short* __restrict__ S_bf, unsigned short* __restrict__ P0_bf,
        unsigned short* __restrict__ P0T_bf, unsigned short* __restrict__ pt_bf,
        int* __restrict__ rowflag, int* __restrict__ cntRow,
        int* __restrict__ done)
{
    int bid = blockIdx.x, t = threadIdx.x;
    int k = bid >> 4, r = bid & 15;
    __shared__ int lab[32], rankS[32], luS[32], ownS[128];
    __shared__ int hist[128], redS[128];
    if (t < 32) lab[t] = labels[t];
    if (t < 128) { hist[t] = 0; ownS[t] = -1; }
    __syncthreads();
    if (t < 32) { int rk = 0; for (int j = 0; j < 32; ++j) rk += (lab[j] < lab[t]); rankS[t] = rk; }
    __syncthreads();
    if (t < 32) luS[rankS[t]] = lab[t];
    __syncthreads();
    if (t < 32) ownS[luS[t]] = t;
    __syncthreads();

    int id = 0, isv = 0;
    if (t < 128) {
        id = relIds[((size_t)rankS[k]*NRELD + r)*PSZ + t];
        isv = (id != PSZ);
        if (isv) atomicAdd(&hist[id], 1);
        redS[t] = id + (isv << 20);          // rowsum (<2^20) | cnt<<20
    }
    __syncthreads();
    for (int off = 64; off; off >>= 1) {
        if (t < off && t < 128) redS[t] += redS[t + off];
        __syncthreads();
    }
    int rowsum = redS[0] & 0xFFFFF;
    int cnt    = redS[0] >> 20;
    int rf     = (rowsum > 0);
    if (t < 128)
        S_bf[(size_t)bid*128 + t] = (unsigned short)f2bf(rf ? (float)hist[t] : 0.f);
    if (t == 0) { rowflag[bid] = rf; cntRow[bid] = cnt; }
    if (bid == 0 && t == 0) done[0] = 0;

    if (bid < 128) {                          // P0 conversions (row p = bid)
        int p = bid;
        float4 v4 = *(const float4*)&P0[(size_t)p*HID + t*4];
        unsigned int b0 = f2bf(v4.x), b1 = f2bf(v4.y), b2 = f2bf(v4.z), b3 = f2bf(v4.w);
        uint2 d; d.x = b0 | (b1 << 16); d.y = b2 | (b3 << 16);
        *(uint2*)&P0_bf[(size_t)p*HID + t*4] = d;
        P0T_bf[(size_t)(t*4+0)*128 + p] = (unsigned short)b0;
        P0T_bf[(size_t)(t*4+1)*128 + p] = (unsigned short)b1;
        P0T_bf[(size_t)(t*4+2)*128 + p] = (unsigned short)b2;
        P0T_bf[(size_t)(t*4+3)*128 + p] = (unsigned short)b3;
        int kk = ownS[p];
        if (kk >= 0) *(uint2*)&pt_bf[(size_t)kk*HID + t*4] = d;
    }
}

// -------------------------------------------------------------------------
// K2 (k_vw): fused v (blocks 0..191) + w (blocks 192..287, zero prop/loss)
// [R3-verbatim]
// -------------------------------------------------------------------------
__global__ __launch_bounds__(256) void k_vw(
        const float* __restrict__ rel, const unsigned short* __restrict__ pt_bf,
        const unsigned short* __restrict__ S_bf, const unsigned short* __restrict__ P0T_bf,
        unsigned short* __restrict__ v_bf, unsigned short* __restrict__ w_bf,
        float* __restrict__ prop, float* __restrict__ lossAcc)
{
    __shared__ unsigned short sh[32*768 + 64*128];
    int bid = blockIdx.x, t = threadIdx.x;
    int wave = t >> 6, lane = t & 63;

    if (bid < 192) {
        int r = bid & 15, hs = bid >> 4;
        unsigned short* ptS = sh;            // [k][g], chunk c^=(k&7)
        unsigned short* AS  = sh + 32*768;   // [h][g-tile 128], chunk c^=(h&7)
        for (int i = t; i < 3072; i += 256) {
            int k = i / 96, c = i % 96;
            uint4 d = *(const uint4*)&pt_bf[(size_t)k*HID + c*8];
            *(uint4*)&ptS[k*768 + (c ^ (k & 7))*8] = d;
        }
        const int gq = (t & 31) * 4;
        const int hr = t >> 5;
        const size_t relbase = ((size_t)r*HID + hs*64) * HID;
        float4 buf[8];
        #pragma unroll
        for (int rr = 0; rr < 8; ++rr)
            buf[rr] = *(const float4*)&rel[relbase + (size_t)(hr + rr*8)*HID + gq];
        f32x4 acc[2] = {{0.f,0.f,0.f,0.f},{0.f,0.f,0.f,0.f}};
        const int arow = wave*16 + (lane & 15);
        for (int gt = 0; gt < 6; ++gt) {
            __syncthreads();
            #pragma unroll
            for (int rr = 0; rr < 8; ++rr) {
                int h_l = hr + rr*8;
                float4 v4 = buf[rr];
                int cs = (gq >> 3) ^ (h_l & 7);
                uint2 d; d.x = f2bf(v4.x) | (f2bf(v4.y) << 16);
                d.y = f2bf(v4.z) | (f2bf(v4.w) << 16);
                *(uint2*)&AS[h_l*128 + cs*8 + (gq & 4)] = d;
            }
            __syncthreads();
            if (gt < 5) {
                int gn = gt*128 + 128;
                #pragma unroll
                for (int rr = 0; rr < 8; ++rr)
                    buf[rr] = *(const float4*)&rel[relbase + (size_t)(hr + rr*8)*HID + gn + gq];
            }
            #pragma unroll
            for (int kk = 0; kk < 4; ++kk) {
                int cA = (kk*4 + (lane >> 4)) ^ (arow & 7);
                bf16x8 a = *(const bf16x8*)&AS[arow*128 + cA*8];
                #pragma unroll
                for (int nf = 0; nf < 2; ++nf) {
                    int k = nf*16 + (lane & 15);
                    int cB = (gt*16 + kk*4 + (lane >> 4)) ^ (k & 7);
                    bf16x8 b = *(const bf16x8*)&ptS[k*768 + cB*8];
                    acc[nf] = __builtin_amdgcn_mfma_f32_16x16x32_bf16(a, b, acc[nf], 0, 0, 0);
                }
            }
        }
        int h_out = hs*64 + wave*16 + (lane >> 4) * 4;
        #pragma unroll
        for (int nf = 0; nf < 2; ++nf) {
            int k = nf*16 + (lane & 15);
            uint2 d; d.x = f2bf(acc[nf][0]) | (f2bf(acc[nf][1]) << 16);
            d.y = f2bf(acc[nf][2]) | (f2bf(acc[nf][3]) << 16);
            *(uint2*)&v_bf[((size_t)k*NRELD + r)*HID + h_out] = d;
        }
    } else {
        int idx = bid - 192;                 // 0..95
        int ms = idx / 12, ns = idx % 12;
        unsigned short* AS2 = sh;
        unsigned short* BS2 = sh + 64*128;
        if (t < 64) *(float4*)&prop[idx*256 + t*4] = float4{0.f,0.f,0.f,0.f};
        if (idx == 0 && t == 0) lossAcc[0] = 0.f;
        for (int i = t; i < 1024; i += 256) {
            int row = i >> 4, c = i & 15;
            *(uint4*)&AS2[row*128 + (c ^ (row & 7))*8] =
                *(const uint4*)&S_bf[(size_t)(ms*64 + row)*128 + c*8];
            *(uint4*)&BS2[row*128 + (c ^ (row & 7))*8] =
                *(const uint4*)&P0T_bf[(size_t)(ns*64 + row)*128 + c*8];
        }
        __syncthreads();
        f32x4 acc[4] = {{0.f,0.f,0.f,0.f},{0.f,0.f,0.f,0.f},{0.f,0.f,0.f,0.f},{0.f,0.f,0.f,0.f}};
        int arow = wave*16 + (lane & 15);
        #pragma unroll
        for (int kk = 0; kk < 4; ++kk) {
            int cA = (kk*4 + (lane >> 4)) ^ (arow & 7);
            bf16x8 a = *(const bf16x8*)&AS2[arow*128 + cA*8];
            #pragma unroll
            for (int nf = 0; nf < 4; ++nf) {
                int brow = nf*16 + (lane & 15);
                int cB = (kk*4 + (lane >> 4)) ^ (brow & 7);
                bf16x8 b = *(const bf16x8*)&BS2[brow*128 + cB*8];
                acc[nf] = __builtin_amdgcn_mfma_f32_16x16x32_bf16(a, b, acc[nf], 0, 0, 0);
            }
        }
        int kr0 = ms*64 + wave*16 + (lane >> 4) * 4;
        #pragma unroll
        for (int nf = 0; nf < 4; ++nf) {
            int h = ns*64 + nf*16 + (lane & 15);
            #pragma unroll
            for (int j = 0; j < 4; ++j)
                w_bf[(size_t)(kr0 + j)*HID + h] = (unsigned short)f2bf(acc[nf][j]);
        }
    }
}

// -------------------------------------------------------------------------
// K3: prop[k,g] += W_r[k,h] x Rel_r[h,g]   grid (16 r, 12 g-slabs), 256 thr
// [R3-verbatim]
// -------------------------------------------------------------------------
__global__ __launch_bounds__(256) void k_prop_mfma(
        const float* __restrict__ rel, const unsigned short* __restrict__ w_bf,
        float* __restrict__ prop)
{
    int r = blockIdx.x, gs = blockIdx.y, t = threadIdx.x;
    int wave = t >> 6, lane = t & 63;
    __shared__ unsigned short WS[32*768];
    __shared__ unsigned short BS[64*128];
    for (int i = t; i < 3072; i += 256) {
        int k = i / 96, c = i % 96;
        uint4 d = *(const uint4*)&w_bf[((size_t)k*NRELD + r)*HID + c*8];
        *(uint4*)&WS[k*768 + (c ^ (k & 7))*8] = d;
    }
    const int gqq = t & 15;
    const int h4  = t >> 4;
    const size_t relb = (size_t)r*HID*HID + (size_t)gs*64;
    float4 buf[8];
    #pragma unroll
    for (int sup = 0; sup < 2; ++sup)
        #pragma unroll
        for (int rr = 0; rr < 4; ++rr)
            buf[sup*4+rr] = *(const float4*)&rel[relb + (size_t)(sup*64 + h4*4 + rr)*HID + gqq*4];
    f32x4 acc[2] = {{0.f,0.f,0.f,0.f},{0.f,0.f,0.f,0.f}};
    for (int ht = 0; ht < 6; ++ht) {
        __syncthreads();
        #pragma unroll
        for (int sup = 0; sup < 2; ++sup) {
            #pragma unroll
            for (int i = 0; i < 4; ++i) {
                int g_l = gqq*4 + i;
                int hloc = sup*64 + h4*4;
                unsigned int p0 = f2bf(((const float*)&buf[sup*4+0])[i]);
                unsigned int p1 = f2bf(((const float*)&buf[sup*4+1])[i]);
                unsigned int p2 = f2bf(((const float*)&buf[sup*4+2])[i]);
                unsigned int p3 = f2bf(((const float*)&buf[sup*4+3])[i]);
                int cs = (hloc >> 3) ^ ((g_l >> 2) & 7);
                uint2 d; d.x = p0 | (p1 << 16); d.y = p2 | (p3 << 16);
                *(uint2*)&BS[g_l*128 + cs*8 + (hloc & 4)] = d;
            }
        }
        __syncthreads();
        if (ht < 5) {
            int hn = ht*128 + 128;
            #pragma unroll
            for (int sup = 0; sup < 2; ++sup)
                #pragma unroll
                for (int rr = 0; rr < 4; ++rr)
                    buf[sup*4+rr] = *(const float4*)&rel[relb + (size_t)(hn + sup*64 + h4*4 + rr)*HID + gqq*4];
        }
        int g_l = wave*16 + (lane & 15);
        #pragma unroll
        for (int kk = 0; kk < 4; ++kk) {
            int cB = (kk*4 + (lane >> 4)) ^ ((g_l >> 2) & 7);
            bf16x8 b = *(const bf16x8*)&BS[g_l*128 + cB*8];
            #pragma unroll
            for (int mf = 0; mf < 2; ++mf) {
                int arow = mf*16 + (lane & 15);
                int cA = (ht*16 + kk*4 + (lane >> 4)) ^ (arow & 7);
                bf16x8 a = *(const bf16x8*)&WS[arow*768 + cA*8];
                acc[mf] = __builtin_amdgcn_mfma_f32_16x16x32_bf16(a, b, acc[mf], 0, 0, 0);
            }
        }
    }
    int gcol = gs*64 + wave*16 + (lane & 15);
    #pragma unroll
    for (int mf = 0; mf < 2; ++mf) {
        int k0 = mf*16 + (lane >> 4)*4;
        #pragma unroll
        for (int j = 0; j < 4; ++j)
            atomicAdd(&prop[(size_t)(k0 + j)*HID + gcol], acc[mf][j]);
    }
}

// -------------------------------------------------------------------------
// K4 (k_tail): 40 blocks x 256 thr
//   bid < 32 : zz GEMM + CE loss; last-done block finalizes outLoss
//   bid >=32 : proto scatter-update + logits (16 p-rows / block)
// [zz from R3 k_zzproto; proto+logits+finalize from R5 k_tail — both proven]
// -------------------------------------------------------------------------
__global__ __launch_bounds__(256) void k_tail(
        const unsigned short* __restrict__ v_bf, const unsigned short* __restrict__ P0_bf,
        const unsigned short* __restrict__ S_bf, float* __restrict__ lossAcc,
        int* __restrict__ done,
        const float* __restrict__ P0, const float* __restrict__ prop,
        const int* __restrict__ rowflag, const int* __restrict__ cntRow,
        const int* __restrict__ labels, const float* __restrict__ inst,
        float* __restrict__ outProto, float* __restrict__ outLogits,
        float* __restrict__ outLoss)
{
    __shared__ __align__(16) char shraw[16*772*4];    // 49408 B union
    __shared__ int lab[32], rankS[32], luS[32], ownS[128];
    __shared__ float redF[256];
    __shared__ int redI[256];
    __shared__ float nActS[16];
    __shared__ int kS2[16];
    const int bid = blockIdx.x, t = threadIdx.x;
    const int wave = t >> 6, lane = t & 63;

    if (t < 32) lab[t] = labels[t];
    if (t < 128) ownS[t] = -1;
    __syncthreads();
    if (t < 32) { int rk = 0; for (int j = 0; j < 32; ++j) rk += (lab[j] < lab[t]); rankS[t] = rk; }
    __syncthreads();
    if (t < 32) luS[rankS[t]] = lab[t];
    __syncthreads();
    if (t < 32) ownS[luS[t]] = t;
    __syncthreads();

    if (bid < 32) {
        // ---- zz + CE loss ----
        int ms = bid;
        unsigned short* AS  = (unsigned short*)shraw;            // 16x128 bf16
        unsigned short* BS2 = (unsigned short*)shraw + 16*128;   // 128x128 bf16
        f32x4 acc[2] = {{0.f,0.f,0.f,0.f},{0.f,0.f,0.f,0.f}};
        for (int ht = 0; ht < 6; ++ht) {
            int h0 = ht * 128;
            __syncthreads();
            {
                int row = t >> 4, c = t & 15;
                *(uint4*)&AS[row*128 + (c ^ (row & 7))*8] =
                    *(const uint4*)&v_bf[(size_t)(ms*16 + row)*HID + h0 + c*8];
                #pragma unroll
                for (int q = 0; q < 8; ++q) {
                    int j2 = t + q*256;
                    int prow = j2 >> 4, c2 = j2 & 15;
                    *(uint4*)&BS2[prow*128 + (c2 ^ (prow & 7))*8] =
                        *(const uint4*)&P0_bf[(size_t)prow*HID + h0 + c2*8];
                }
            }
            __syncthreads();
            int arow = lane & 15;
            #pragma unroll
            for (int kk = 0; kk < 4; ++kk) {
                int cA = (kk*4 + (lane >> 4)) ^ (arow & 7);
                bf16x8 a = *(const bf16x8*)&AS[arow*128 + cA*8];
                #pragma unroll
                for (int nf = 0; nf < 2; ++nf) {
                    int brow = wave*32 + nf*16 + (lane & 15);
                    int cB = (kk*4 + (lane >> 4)) ^ (brow & 7);
                    bf16x8 b = *(const bf16x8*)&BS2[brow*128 + cB*8];
                    acc[nf] = __builtin_amdgcn_mfma_f32_16x16x32_bf16(a, b, acc[nf], 0, 0, 0);
                }
            }
        }
        float term = 0.f;
        #pragma unroll
        for (int nf = 0; nf < 2; ++nf) {
            int p = wave*32 + nf*16 + (lane & 15);
            int kr0 = ms*16 + (lane >> 4)*4;
            #pragma unroll
            for (int j = 0; j < 4; ++j) {
                float S = bf2f(S_bf[(size_t)(kr0 + j)*128 + p]);
                if (S != 0.f) {
                    float z = acc[nf][j];
                    float s = 1.f / (1.f + expf(-z));
                    term += S * (logf(expf(1.f - s) + expf(s)) - s);
                }
            }
        }
        redF[t] = term;
        __syncthreads();
        for (int off = 128; off; off >>= 1) {
            if (t < off) redF[t] += redF[t + off];
            __syncthreads();
        }
        if (t == 0) atomicAdd(lossAcc, redF[0]);
        __threadfence();
        __syncthreads();
        float s2 = 0.f; int tot = 0;
        #pragma unroll
        for (int q = 0; q < 2; ++q) {
            int rr2 = t + 256*q;
            int rf = rowflag[rr2];
            tot |= rf;
            if (rf) s2 += (float)cntRow[rr2];
        }
        redF[t] = s2; redI[t] = tot;
        __syncthreads();
        for (int off = 128; off; off >>= 1) {
            if (t < off) { redF[t] += redF[t + off]; redI[t] |= redI[t + off]; }
            __syncthreads();
        }
        if (t == 0) {
            int old = atomicAdd(done, 1);
            if (old == 31) {
                __threadfence();
                float cur = atomicAdd(lossAcc, 0.f);   // atomic read of final sum
                outLoss[0] = redI[0]
                    ? (cur + (65536.f - redF[0]) * 0.6931471805599453f) * (1.f/65536.f)
                    : 0.f;
            }
        }
    } else {
        // ---- proto update + logits, 16 p-rows per block ----
        float* protoS = (float*)shraw;       // [16][772] padded
        const int PSTR = 772;
        int pb = (bid - 32) * 16;
        if (t < 16) {
            int p = pb + t;
            int k = ownS[p];
            float n = 0.f;
            if (k >= 0)
                for (int i = 0; i < 16; ++i) {
                    int rr2 = k*NRELD + i;
                    if (rowflag[rr2]) n += (float)cntRow[rr2];
                }
            nActS[t] = n; kS2[t] = k;
        }
        __syncthreads();
        for (int it = t; it < 16*192; it += 256) {
            int pl = it / 192, c = it % 192;
            int p = pb + pl;
            float4 old = *(const float4*)&P0[(size_t)p*HID + c*4];
            float4 o = old;
            int k = kS2[pl]; float n = nActS[pl];
            if (k >= 0 && n > 0.f) {
                float4 pr = *(const float4*)&prop[(size_t)k*HID + c*4];
                float invn = 0.5f / n;
                o.x = 0.5f*old.x + pr.x*invn;
                o.y = 0.5f*old.y + pr.y*invn;
                o.z = 0.5f*old.z + pr.z*invn;
                o.w = 0.5f*old.w + pr.w*invn;
            }
            *(float4*)&outProto[(size_t)p*HID + c*4] = o;
            protoS[pl*PSTR + c*4+0] = o.x;
            protoS[pl*PSTR + c*4+1] = o.y;
            protoS[pl*PSTR + c*4+2] = o.z;
            protoS[pl*PSTR + c*4+3] = o.w;
        }
        __syncthreads();
        int b = t & 31, p2 = (t >> 5) * 2;
        const float4* ir = (const float4*)&inst[(size_t)b*HID];
        float a0 = 0.f, a1 = 0.f;
        for (int q = 0; q < HID/4; ++q) {
            float4 iv = ir[q];
            float4 pv0 = *(const float4*)&protoS[p2*PSTR + q*4];
            float4 pv1 = *(const float4*)&protoS[(p2+1)*PSTR + q*4];
            float dx = iv.x - pv0.x, dy = iv.y - pv0.y, dz = iv.z - pv0.z, dw = iv.w - pv0.w;
            a0 += dx*dx + dy*dy + dz*dz + dw*dw;
            dx = iv.x - pv1.x; dy = iv.y - pv1.y; dz = iv.z - pv1.z; dw = iv.w - pv1.w;
            a1 += dx*dx + dy*dy + dz*dz + dw*dw;
        }
        outLogits[b*PSZ + pb + p2]     = -a0;
        outLogits[b*PSZ + pb + p2 + 1] = -a1;
    }
}

// -------------------------------------------------------------------------
extern "C" void kernel_launch(void* const* d_in, const int* in_sizes, int n_in,
                              void* d_out, int out_size, void* d_ws, size_t ws_size,
                              hipStream_t stream)
{
    const float* inst  = (const float*)d_in[0];   // [32,768]
    const float* rel   = (const float*)d_in[1];   // [16,768,768]
    const int* relIds  = (const int*)d_in[2];     // [32,16,128]
    const int* labels  = (const int*)d_in[3];     // [32]
    const float* P0    = (const float*)d_in[4];   // [128,768]
    float* out = (float*)d_out;
    float* outLogits = out;            // 4096
    float* outLoss   = out + 4096;     // 1
    float* outProto  = out + 4097;     // 98304

    char* ws = (char*)d_ws;
    unsigned short* v_bf    = (unsigned short*)(ws + 0);        // 786432 B
    unsigned short* w_bf    = (unsigned short*)(ws + 786432);   // 786432 B
    unsigned short* S_bf    = (unsigned short*)(ws + 1572864);  // 131072 B
    unsigned short* P0_bf   = (unsigned short*)(ws + 1703936);  // 196608 B
    unsigned short* P0T_bf  = (unsigned short*)(ws + 1900544);  // 196608 B
    unsigned short* pt_bf   = (unsigned short*)(ws + 2097152);  // 49152 B
    float* prop    = (float*)(ws + 2146304);                    // 98304 B
    float* lossAcc = (float*)(ws + 2244608);                    // 128 B
    int*   done    = (int*)(ws + 2244736);                      // 128 B
    int*   rowflag = (int*)(ws + 2244864);                      // 2048 B
    int*   cntRow  = (int*)(ws + 2246912);                      // 2048 B

    k_prep<<<512, 192, 0, stream>>>(labels, relIds, P0, S_bf, P0_bf, P0T_bf,
                                    pt_bf, rowflag, cntRow, done);
    k_vw<<<288, 256, 0, stream>>>(rel, pt_bf, S_bf, P0T_bf, v_bf, w_bf,
                                  prop, lossAcc);
    k_prop_mfma<<<dim3(16,12), 256, 0, stream>>>(rel, w_bf, prop);
    k_tail<<<40, 256, 0, stream>>>(v_bf, P0_bf, S_bf, lossAcc, done, P0, prop,
                                   rowflag, cntRow, labels, inst,
                                   outProto, outLogits, outLoss);
}

// Round 7
// 128.124 us; speedup vs baseline: 1.9533x; 1.0696x over previous
//
#include <hip/hip_runtime.h>
#include <hip/hip_bf16.h>
#include <math.h>

#define K_B 32
#define NRELD 16
#define PSZ 128
#define HID 768

using bf16x8 = __attribute__((ext_vector_type(8))) short;
using f32x4  = __attribute__((ext_vector_type(4))) float;

__device__ __forceinline__ unsigned int f2bf(float x) {   // fp32 -> bf16 bits (RNE)
    unsigned int u = __float_as_uint(x);
    return (u + 0x7fffu + ((u >> 16) & 1u)) >> 16;
}
__device__ __forceinline__ float bf2f(unsigned short b) {
    return __uint_as_float(((unsigned int)b) << 16);
}

// -------------------------------------------------------------------------
// K1 (k_prep): per-(k,r) gated histogram S + rowflag/cntRow; blocks<128
// convert P0 (P0_bf, pt_bf); blocks<96 zero prop; block 0 zeroes loss/done.
// grid 512 (k*16+r), 192 thr
// -------------------------------------------------------------------------
__global__ __launch_bounds__(192) void k_prep(
        const int* __restrict__ labels, const int* __restrict__ relIds,
        const float* __restrict__ P0,
        unsigned short* __restrict__ S_bf, unsigned short* __restrict__ P0_bf,
        unsigned short* __restrict__ pt_bf,
        int* __restrict__ rowflag, int* __restrict__ cntRow,
        float* __restrict__ prop, float* __restrict__ lossAcc,
        int* __restrict__ done)
{
    int bid = blockIdx.x, t = threadIdx.x;
    int k = bid >> 4, r = bid & 15;
    __shared__ int lab[32], rankS[32], luS[32], ownS[128];
    __shared__ int hist[128], redS[128];
    if (t < 32) lab[t] = labels[t];
    if (t < 128) { hist[t] = 0; ownS[t] = -1; }
    __syncthreads();
    if (t < 32) { int rk = 0; for (int j = 0; j < 32; ++j) rk += (lab[j] < lab[t]); rankS[t] = rk; }
    __syncthreads();
    if (t < 32) luS[rankS[t]] = lab[t];
    __syncthreads();
    if (t < 32) ownS[luS[t]] = t;
    __syncthreads();

    if (t < 128) {
        int id = relIds[((size_t)rankS[k]*NRELD + r)*PSZ + t];
        int isv = (id != PSZ);
        if (isv) atomicAdd(&hist[id], 1);
        redS[t] = id + (isv << 20);          // rowsum (<2^20) | cnt<<20
    }
    __syncthreads();
    for (int off = 64; off; off >>= 1) {
        if (t < off) redS[t] += redS[t + off];
        __syncthreads();
    }
    int rowsum = redS[0] & 0xFFFFF;
    int cnt    = redS[0] >> 20;
    int rf     = (rowsum > 0);
    if (t < 128)
        S_bf[(size_t)bid*128 + t] = (unsigned short)f2bf(rf ? (float)hist[t] : 0.f);
    if (t == 0) { rowflag[bid] = rf; cntRow[bid] = cnt; }
    if (bid == 0 && t == 0) { lossAcc[0] = 0.f; done[0] = 0; }
    if (bid < 96 && t < 64) {                 // zero prop (32x768 f32)
        float4 z = {0.f, 0.f, 0.f, 0.f};
        ((float4*)prop)[bid*64 + t] = z;
    }
    if (bid < 128) {                          // P0 conversions (row p = bid)
        int p = bid;
        float4 v4 = *(const float4*)&P0[(size_t)p*HID + t*4];
        unsigned int b0 = f2bf(v4.x), b1 = f2bf(v4.y), b2 = f2bf(v4.z), b3 = f2bf(v4.w);
        uint2 d; d.x = b0 | (b1 << 16); d.y = b2 | (b3 << 16);
        *(uint2*)&P0_bf[(size_t)p*HID + t*4] = d;
        int kk = ownS[p];
        if (kk >= 0) *(uint2*)&pt_bf[(size_t)kk*HID + t*4] = d;
    }
}

// -------------------------------------------------------------------------
// K2 (k_Y): Y_r = P0 x Rel_r  (contraction h, rel transposed in LDS)
//   + fused prop-tile: prop[k, g-slab] += S_r x Ytile
// grid 384 (r = bid&15, gs = bid>>4: 24 g-slabs of 32), 256 thr, 40 KB LDS
// -------------------------------------------------------------------------
__global__ __launch_bounds__(256) void k_Y(
        const float* __restrict__ rel, const unsigned short* __restrict__ P0_bf,
        const unsigned short* __restrict__ S_bf,
        unsigned short* __restrict__ Y_bf, float* __restrict__ prop)
{
    __shared__ unsigned short sh[16384 + 4096];   // AS 128x128 | BS 32x128
    unsigned short* AS  = sh;                     // [p][h-chunk], c^=(p&7)
    unsigned short* BS  = sh + 16384;             // [g][h-chunk], c^=((g>>2)&7)
    unsigned short* YST = sh;                     // phase2: [g][p], aliases AS
    unsigned short* SS  = sh + 4096;              // phase2: [k][p], aliases AS

    const int bid = blockIdx.x, t = threadIdx.x;
    const int wave = t >> 6, lane = t & 63;
    const int r = bid & 15, gs = bid >> 4;
    const int g0 = gs * 32;

    const int gq2 = t & 7;                   // float4-in-g (g_l = gq2*4)
    const int hq  = t >> 3;                  // 0..31  (h rows hq*4 .. +3)
    const size_t relb = (size_t)r*HID*HID + g0;

    float4 buf[4];
    #pragma unroll
    for (int rr = 0; rr < 4; ++rr)
        buf[rr] = *(const float4*)&rel[relb + (size_t)(hq*4 + rr)*HID + gq2*4];

    f32x4 acc[2][2] = {{{0.f,0.f,0.f,0.f},{0.f,0.f,0.f,0.f}},
                       {{0.f,0.f,0.f,0.f},{0.f,0.f,0.f,0.f}}};

    for (int ch = 0; ch < 6; ++ch) {
        __syncthreads();
        // transpose-pack rel chunk -> BS[g][h]
        #pragma unroll
        for (int i = 0; i < 4; ++i) {
            int g_l = gq2*4 + i;
            int hloc = hq*4;
            unsigned int p0 = f2bf(((const float*)&buf[0])[i]);
            unsigned int p1 = f2bf(((const float*)&buf[1])[i]);
            unsigned int p2 = f2bf(((const float*)&buf[2])[i]);
            unsigned int p3 = f2bf(((const float*)&buf[3])[i]);
            int cs = (hloc >> 3) ^ ((g_l >> 2) & 7);
            uint2 d; d.x = p0 | (p1 << 16); d.y = p2 | (p3 << 16);
            *(uint2*)&BS[g_l*128 + cs*8 + (hloc & 4)] = d;
        }
        // stage P0 chunk -> AS[p][h]
        #pragma unroll
        for (int q = 0; q < 8; ++q) {
            int idx = t + q*256;
            int row = idx >> 4, c = idx & 15;
            *(uint4*)&AS[row*128 + (c ^ (row & 7))*8] =
                *(const uint4*)&P0_bf[(size_t)row*HID + ch*128 + c*8];
        }
        __syncthreads();
        if (ch < 5) {
            int hn = ch*128 + 128;
            #pragma unroll
            for (int rr = 0; rr < 4; ++rr)
                buf[rr] = *(const float4*)&rel[relb + (size_t)(hn + hq*4 + rr)*HID + gq2*4];
        }
        #pragma unroll
        for (int kk = 0; kk < 4; ++kk) {
            #pragma unroll
            for (int mf = 0; mf < 2; ++mf) {
                int arow = wave*32 + mf*16 + (lane & 15);
                int cA = (kk*4 + (lane >> 4)) ^ (arow & 7);
                bf16x8 a = *(const bf16x8*)&AS[arow*128 + cA*8];
                #pragma unroll
                for (int nf = 0; nf < 2; ++nf) {
                    int brow = nf*16 + (lane & 15);
                    int cB = (kk*4 + (lane >> 4)) ^ ((brow >> 2) & 7);
                    bf16x8 b = *(const bf16x8*)&BS[brow*128 + cB*8];
                    acc[mf][nf] = __builtin_amdgcn_mfma_f32_16x16x32_bf16(a, b, acc[mf][nf], 0, 0, 0);
                }
            }
        }
    }
    __syncthreads();   // AS/BS dead; alias as YST/SS

    // write Y tile (global, [r][p][g]) + YST (LDS, [g][p] swizzled)
    #pragma unroll
    for (int mf = 0; mf < 2; ++mf) {
        #pragma unroll
        for (int nf = 0; nf < 2; ++nf) {
            #pragma unroll
            for (int j = 0; j < 4; ++j) {
                int p = wave*32 + mf*16 + (lane >> 4)*4 + j;
                int g_l = nf*16 + (lane & 15);
                unsigned short yb = (unsigned short)f2bf(acc[mf][nf][j]);
                Y_bf[((size_t)r*128 + p)*HID + g0 + g_l] = yb;
                YST[g_l*128 + (((p >> 3) ^ ((g_l >> 2) & 7))*8) + (p & 7)] = yb;
            }
        }
    }
    // stage S_r -> SS[k][p]
    #pragma unroll
    for (int q = 0; q < 2; ++q) {
        int idx = t + q*256;
        int row = idx >> 4, c = idx & 15;
        *(uint4*)&SS[row*128 + (c ^ (row & 7))*8] =
            *(const uint4*)&S_bf[((size_t)row*NRELD + r)*128 + c*8];
    }
    __syncthreads();
    // prop tile: [32 k x 32 g] = S_r[32x128] x Ytile[128x32g]; waves 0,1
    if (wave < 2) {
        f32x4 acc2[2] = {{0.f,0.f,0.f,0.f},{0.f,0.f,0.f,0.f}};
        #pragma unroll
        for (int kk = 0; kk < 4; ++kk) {
            int brow = wave*16 + (lane & 15);
            int cB = (kk*4 + (lane >> 4)) ^ ((brow >> 2) & 7);
            bf16x8 b = *(const bf16x8*)&YST[brow*128 + cB*8];
            #pragma unroll
            for (int mf = 0; mf < 2; ++mf) {
                int arow = mf*16 + (lane & 15);
                int cA = (kk*4 + (lane >> 4)) ^ (arow & 7);
                bf16x8 a = *(const bf16x8*)&SS[arow*128 + cA*8];
                acc2[mf] = __builtin_amdgcn_mfma_f32_16x16x32_bf16(a, b, acc2[mf], 0, 0, 0);
            }
        }
        int gg = g0 + wave*16 + (lane & 15);
        #pragma unroll
        for (int mf = 0; mf < 2; ++mf) {
            #pragma unroll
            for (int j = 0; j < 4; ++j) {
                int kkk = mf*16 + (lane >> 4)*4 + j;
                atomicAdd(&prop[(size_t)kkk*HID + gg], acc2[mf][j]);
            }
        }
    }
}

// -------------------------------------------------------------------------
// K3 (k_tail): 24 blocks x 256 thr
//   bid < 16 : zz_r = Y_r x pt^T (K=768 over g) + CE loss; done-counter
//              finalize of outLoss by last zz block
//   bid >=16 : proto scatter-update + logits (16 p-rows / block)
// -------------------------------------------------------------------------
__global__ __launch_bounds__(256) void k_tail(
        const unsigned short* __restrict__ Y_bf, const unsigned short* __restrict__ pt_bf,
        const unsigned short* __restrict__ S_bf, float* __restrict__ lossAcc,
        int* __restrict__ done,
        const float* __restrict__ P0, const float* __restrict__ prop,
        const int* __restrict__ rowflag, const int* __restrict__ cntRow,
        const int* __restrict__ labels, const float* __restrict__ inst,
        float* __restrict__ outProto, float* __restrict__ outLogits,
        float* __restrict__ outLoss)
{
    __shared__ __align__(16) char shraw[81920];   // ptS 48K + AS 32K | protoS 49.4K
    __shared__ int lab[32], rankS[32], luS[32], ownS[128];
    __shared__ float redF[256];
    __shared__ int redI[256];
    __shared__ float nActS[16];
    __shared__ int kS2[16];
    const int bid = blockIdx.x, t = threadIdx.x;
    const int wave = t >> 6, lane = t & 63;

    if (t < 32) lab[t] = labels[t];
    if (t < 128) ownS[t] = -1;
    __syncthreads();
    if (t < 32) { int rk = 0; for (int j = 0; j < 32; ++j) rk += (lab[j] < lab[t]); rankS[t] = rk; }
    __syncthreads();
    if (t < 32) luS[rankS[t]] = lab[t];
    __syncthreads();
    if (t < 32) ownS[luS[t]] = t;
    __syncthreads();

    if (bid < 16) {
        // ---- zz_r + CE loss ----
        const int r = bid;
        unsigned short* ptS = (unsigned short*)shraw;            // [k][g], c^=(k&7)
        unsigned short* AS  = (unsigned short*)shraw + 24576;    // [p][g-chunk], c^=(p&7)
        for (int i = t; i < 3072; i += 256) {
            int k = i / 96, c = i % 96;
            uint4 d = *(const uint4*)&pt_bf[(size_t)k*HID + c*8];
            *(uint4*)&ptS[k*768 + (c ^ (k & 7))*8] = d;
        }
        f32x4 acc[2][2] = {{{0.f,0.f,0.f,0.f},{0.f,0.f,0.f,0.f}},
                           {{0.f,0.f,0.f,0.f},{0.f,0.f,0.f,0.f}}};
        for (int ch = 0; ch < 6; ++ch) {
            __syncthreads();
            #pragma unroll
            for (int q = 0; q < 8; ++q) {
                int idx = t + q*256;
                int row = idx >> 4, c = idx & 15;
                *(uint4*)&AS[row*128 + (c ^ (row & 7))*8] =
                    *(const uint4*)&Y_bf[((size_t)r*128 + row)*HID + ch*128 + c*8];
            }
            __syncthreads();
            #pragma unroll
            for (int kk = 0; kk < 4; ++kk) {
                #pragma unroll
                for (int mf = 0; mf < 2; ++mf) {
                    int arow = wave*32 + mf*16 + (lane & 15);
                    int cA = (kk*4 + (lane >> 4)) ^ (arow & 7);
                    bf16x8 a = *(const bf16x8*)&AS[arow*128 + cA*8];
                    #pragma unroll
                    for (int nf = 0; nf < 2; ++nf) {
                        int brow = nf*16 + (lane & 15);
                        int cB = (ch*16 + kk*4 + (lane >> 4)) ^ (brow & 7);
                        bf16x8 b = *(const bf16x8*)&ptS[brow*768 + cB*8];
                        acc[mf][nf] = __builtin_amdgcn_mfma_f32_16x16x32_bf16(a, b, acc[mf][nf], 0, 0, 0);
                    }
                }
            }
        }
        float term = 0.f;
        #pragma unroll
        for (int mf = 0; mf < 2; ++mf) {
            #pragma unroll
            for (int nf = 0; nf < 2; ++nf) {
                #pragma unroll
                for (int j = 0; j < 4; ++j) {
                    int p = wave*32 + mf*16 + (lane >> 4)*4 + j;
                    int kkk = nf*16 + (lane & 15);
                    float S = bf2f(S_bf[((size_t)kkk*NRELD + r)*128 + p]);
                    if (S != 0.f) {
                        float z = acc[mf][nf][j];
                        float s = 1.f / (1.f + expf(-z));
                        term += S * (logf(expf(1.f - s) + expf(s)) - s);
                    }
                }
            }
        }
        redF[t] = term;
        __syncthreads();
        for (int off = 128; off; off >>= 1) {
            if (t < off) redF[t] += redF[t + off];
            __syncthreads();
        }
        if (t == 0) atomicAdd(lossAcc, redF[0]);
        __threadfence();
        __syncthreads();
        float s2 = 0.f; int tot = 0;
        #pragma unroll
        for (int q = 0; q < 2; ++q) {
            int rr2 = t + 256*q;
            int rf = rowflag[rr2];
            tot |= rf;
            if (rf) s2 += (float)cntRow[rr2];
        }
        redF[t] = s2; redI[t] = tot;
        __syncthreads();
        for (int off = 128; off; off >>= 1) {
            if (t < off) { redF[t] += redF[t + off]; redI[t] |= redI[t + off]; }
            __syncthreads();
        }
        if (t == 0) {
            int old = atomicAdd(done, 1);
            if (old == 15) {
                __threadfence();
                float cur = atomicAdd(lossAcc, 0.f);   // atomic read of final sum
                outLoss[0] = redI[0]
                    ? (cur + (65536.f - redF[0]) * 0.6931471805599453f) * (1.f/65536.f)
                    : 0.f;
            }
        }
    } else {
        // ---- proto update + logits, 16 p-rows per block ----
        float* protoS = (float*)shraw;       // [16][772] padded
        const int PSTR = 772;
        int pb = (bid - 16) * 16;
        if (t < 16) {
            int p = pb + t;
            int k = ownS[p];
            float n = 0.f;
            if (k >= 0)
                for (int i = 0; i < 16; ++i) {
                    int rr2 = k*NRELD + i;
                    if (rowflag[rr2]) n += (float)cntRow[rr2];
                }
            nActS[t] = n; kS2[t] = k;
        }
        __syncthreads();
        for (int it = t; it < 16*192; it += 256) {
            int pl = it / 192, c = it % 192;
            int p = pb + pl;
            float4 old = *(const float4*)&P0[(size_t)p*HID + c*4];
            float4 o = old;
            int k = kS2[pl]; float n = nActS[pl];
            if (k >= 0 && n > 0.f) {
                float4 pr = *(const float4*)&prop[(size_t)k*HID + c*4];
                float invn = 0.5f / n;
                o.x = 0.5f*old.x + pr.x*invn;
                o.y = 0.5f*old.y + pr.y*invn;
                o.z = 0.5f*old.z + pr.z*invn;
                o.w = 0.5f*old.w + pr.w*invn;
            }
            *(float4*)&outProto[(size_t)p*HID + c*4] = o;
            protoS[pl*PSTR + c*4+0] = o.x;
            protoS[pl*PSTR + c*4+1] = o.y;
            protoS[pl*PSTR + c*4+2] = o.z;
            protoS[pl*PSTR + c*4+3] = o.w;
        }
        __syncthreads();
        int b = t & 31, p2 = (t >> 5) * 2;
        const float4* ir = (const float4*)&inst[(size_t)b*HID];
        float a0 = 0.f, a1 = 0.f;
        for (int q = 0; q < HID/4; ++q) {
            float4 iv = ir[q];
            float4 pv0 = *(const float4*)&protoS[p2*PSTR + q*4];
            float4 pv1 = *(const float4*)&protoS[(p2+1)*PSTR + q*4];
            float dx = iv.x - pv0.x, dy = iv.y - pv0.y, dz = iv.z - pv0.z, dw = iv.w - pv0.w;
            a0 += dx*dx + dy*dy + dz*dz + dw*dw;
            dx = iv.x - pv1.x; dy = iv.y - pv1.y; dz = iv.z - pv1.z; dw = iv.w - pv1.w;
            a1 += dx*dx + dy*dy + dz*dz + dw*dw;
        }
        outLogits[b*PSZ + pb + p2]     = -a0;
        outLogits[b*PSZ + pb + p2 + 1] = -a1;
    }
}

// -------------------------------------------------------------------------
extern "C" void kernel_launch(void* const* d_in, const int* in_sizes, int n_in,
                              void* d_out, int out_size, void* d_ws, size_t ws_size,
                              hipStream_t stream)
{
    const float* inst  = (const float*)d_in[0];   // [32,768]
    const float* rel   = (const float*)d_in[1];   // [16,768,768]
    const int* relIds  = (const int*)d_in[2];     // [32,16,128]
    const int* labels  = (const int*)d_in[3];     // [32]
    const float* P0    = (const float*)d_in[4];   // [128,768]
    float* out = (float*)d_out;
    float* outLogits = out;            // 4096
    float* outLoss   = out + 4096;     // 1
    float* outProto  = out + 4097;     // 98304

    char* ws = (char*)d_ws;
    unsigned short* Y_bf    = (unsigned short*)(ws + 0);        // 3145728 B
    unsigned short* S_bf    = (unsigned short*)(ws + 3145728);  // 131072 B
    unsigned short* P0_bf   = (unsigned short*)(ws + 3276800);  // 196608 B
    unsigned short* pt_bf   = (unsigned short*)(ws + 3473408);  // 49152 B
    float* prop    = (float*)(ws + 3522560);                    // 98304 B
    float* lossAcc = (float*)(ws + 3620864);                    // 128 B
    int*   done    = (int*)(ws + 3620992);                      // 128 B
    int*   rowflag = (int*)(ws + 3621120);                      // 2048 B
    int*   cntRow  = (int*)(ws + 3623168);                      // 2048 B

    k_prep<<<512, 192, 0, stream>>>(labels, relIds, P0, S_bf, P0_bf, pt_bf,
                                    rowflag, cntRow, prop, lossAcc, done);
    k_Y<<<384, 256, 0, stream>>>(rel, P0_bf, S_bf, Y_bf, prop);
    k_tail<<<24, 256, 0, stream>>>(Y_bf, pt_bf, S_bf, lossAcc, done, P0, prop,
                                   rowflag, cntRow, labels, inst,
                                   outProto, outLogits, outLoss);
}